// Round 1
// baseline (851.913 us; speedup 1.0000x reference)
//
#include <hip/hip_runtime.h>
#include <hip/hip_bf16.h>
#include <math.h>

typedef float f32x4 __attribute__((ext_vector_type(4)));
typedef __bf16 bf16x8 __attribute__((ext_vector_type(8)));
typedef __bf16 bf16x4 __attribute__((ext_vector_type(4)));

// Problem constants
// B=16, C=768, CLS=20, HEADS=4, dh=192, N=1024 (32x32), 2C=1536

// Workspace layout (bytes), all 16B aligned. Total ~85.9 MB.
static constexpr size_t OFF_XT   = 0;            // bf16 [16][1024][768]  x transposed
static constexpr size_t OFF_KV   = 25165824;     // bf16 [16][1536][1024]
static constexpr size_t OFF_WB   = 75497472;     // bf16 [1536][768]  Wkv*nx_w
static constexpr size_t OFF_RS   = 77856768;     // f32  [1536] rowsum
static constexpr size_t OFF_CST  = 77862912;     // f32  [1536] const term
static constexpr size_t OFF_PART = 77869056;     // f32  [3072][2] partial sums
static constexpr size_t OFF_ST   = 77893632;     // f32  [16][2] mu,rstd
static constexpr size_t OFF_WQT  = 77893760;     // f32  [768][768]
static constexpr size_t OFF_WPT  = 80253056;     // f32  [768][768]
static constexpr size_t OFF_Q    = 82612352;     // f32  [16][20][768]
static constexpr size_t OFF_AO   = 83595392;     // f32  [16][20][768]
static constexpr size_t OFF_OP   = 84578432;     // f32  [16][20][1024]

// ---------------------------------------------------------------------------
// K1: x [b][c][n] f32 -> xT [b][n][c] bf16, plus per-block partial sum/sumsq
__global__ __launch_bounds__(256) void transpose_reduce(
    const float* __restrict__ x, __hip_bfloat16* __restrict__ xT,
    float* __restrict__ part) {
  __shared__ __hip_bfloat16 tile[64][66];
  __shared__ float red[4][2];
  int b = blockIdx.x, cb = blockIdx.y, nb = blockIdx.z;
  int t = threadIdx.x;
  const float* src = x + ((size_t)b * 768 + cb * 64) * 1024 + nb * 64;
  float s1 = 0.f, s2 = 0.f;
#pragma unroll
  for (int i = 0; i < 16; ++i) {
    int idx = i * 256 + t;
    int c = idx >> 6, n = idx & 63;
    float v = src[(size_t)c * 1024 + n];
    s1 += v; s2 += v * v;
    tile[c][n] = __float2bfloat16(v);
  }
#pragma unroll
  for (int o = 32; o > 0; o >>= 1) {
    s1 += __shfl_down(s1, o);
    s2 += __shfl_down(s2, o);
  }
  int wid = t >> 6, lane = t & 63;
  if (lane == 0) { red[wid][0] = s1; red[wid][1] = s2; }
  __syncthreads();
  if (t == 0) {
    float a = 0.f, bb = 0.f;
    for (int w = 0; w < 4; ++w) { a += red[w][0]; bb += red[w][1]; }
    int pidx = b * 192 + cb * 16 + nb;
    part[pidx * 2] = a; part[pidx * 2 + 1] = bb;
  }
  __hip_bfloat16* dst = xT + ((size_t)b * 1024 + nb * 64) * 768 + cb * 64;
#pragma unroll
  for (int i = 0; i < 16; ++i) {
    int idx = i * 256 + t;
    int n = idx >> 6, c = idx & 63;
    dst[(size_t)n * 768 + c] = tile[c][n];
  }
}

// ---------------------------------------------------------------------------
// K2: finalize per-batch mu / rstd
__global__ void finalize_stats(const float* __restrict__ part, float* __restrict__ st) {
  int t = threadIdx.x;
  if (t < 16) {
    float s1 = 0.f, s2 = 0.f;
    for (int i = 0; i < 192; ++i) {
      s1 += part[(t * 192 + i) * 2];
      s2 += part[(t * 192 + i) * 2 + 1];
    }
    float mu = s1 * (1.0f / 786432.0f);
    float var = s2 * (1.0f / 786432.0f) - mu * mu;
    st[t * 2] = mu;
    st[t * 2 + 1] = rsqrtf(var + 1e-5f);
  }
}

// ---------------------------------------------------------------------------
// K3: W' = Wkv * nx_w (bf16), rowsum = sum_c W', cst = sum_c Wkv*nx_b + bkv
__global__ __launch_bounds__(256) void prep_wkv(
    const float* __restrict__ Wkv, const float* __restrict__ nxw,
    const float* __restrict__ nxb, const float* __restrict__ bkv,
    __hip_bfloat16* __restrict__ Wb, float* __restrict__ rowsum,
    float* __restrict__ cst) {
  int o = blockIdx.x * 4 + (threadIdx.x >> 6);
  int lane = threadIdx.x & 63;
  const float* wrow = Wkv + (size_t)o * 768;
  float rs = 0.f, cs = 0.f;
#pragma unroll
  for (int i = 0; i < 12; ++i) {
    int c = lane + i * 64;
    float w = wrow[c];
    float wb = w * nxw[c];
    Wb[(size_t)o * 768 + c] = __float2bfloat16(wb);
    rs += wb;
    cs += w * nxb[c];
  }
#pragma unroll
  for (int off = 32; off > 0; off >>= 1) {
    rs += __shfl_down(rs, off);
    cs += __shfl_down(cs, off);
  }
  if (lane == 0) { rowsum[o] = rs; cst[o] = cs + bkv[o]; }
}

// ---------------------------------------------------------------------------
// K3b: transpose Wq, Wp -> WqT, WpT (f32)
__global__ __launch_bounds__(256) void transpose_w(
    const float* __restrict__ Wq, const float* __restrict__ Wp,
    float* __restrict__ WqT, float* __restrict__ WpT) {
  __shared__ float tl[64][65];
  const float* src = blockIdx.z ? Wp : Wq;
  float* dst = blockIdx.z ? WpT : WqT;
  int ot = blockIdx.x * 64, ct = blockIdx.y * 64;
  int t = threadIdx.x;
#pragma unroll
  for (int i = 0; i < 16; ++i) {
    int idx = i * 256 + t;
    int o = idx >> 6, c = idx & 63;
    tl[o][c] = src[(size_t)(ot + o) * 768 + ct + c];
  }
  __syncthreads();
#pragma unroll
  for (int i = 0; i < 16; ++i) {
    int idx = i * 256 + t;
    int c = idx >> 6, o = idx & 63;
    dst[(size_t)(ct + c) * 768 + ot + o] = tl[o][c];
  }
}

// ---------------------------------------------------------------------------
// K4: kv = rstd*(W' @ x) + (cst - rstd*mu*rowsum), bf16 MFMA, 128x128 tile
__global__ __launch_bounds__(256) void gemm_kv(
    const __hip_bfloat16* __restrict__ Wb, const __hip_bfloat16* __restrict__ xT,
    const float* __restrict__ rowsum, const float* __restrict__ cst,
    const float* __restrict__ st, __hip_bfloat16* __restrict__ kv) {
  __shared__ __hip_bfloat16 As[128 * 64];
  __shared__ __hip_bfloat16 Bs[128 * 64];
  int gx = blockIdx.x;                       // 1536 blocks
  int wg = (gx & 7) * 192 + (gx >> 3);       // bijective XCD swizzle (1536 % 8 == 0)
  int mt = wg % 12;
  int colt = wg / 12;                        // 0..127
  int b = colt >> 3;
  int nt = colt & 7;
  int t = threadIdx.x;
  int wid = t >> 6, lane = t & 63;
  int wm = wid >> 1, wn = wid & 1;

  const __hip_bfloat16* Abase = Wb + (size_t)(mt * 128) * 768;
  const __hip_bfloat16* Bbase = xT + (size_t)b * 1024 * 768 + (size_t)(nt * 128) * 768;

  f32x4 acc[4][4] = {};

  for (int kt = 0; kt < 12; ++kt) {
    const __hip_bfloat16* ag = Abase + kt * 64;
    const __hip_bfloat16* bg = Bbase + kt * 64;
#pragma unroll
    for (int i = 0; i < 4; ++i) {
      int idx = i * 256 + t;
      int row = idx >> 3;
      int kc = (idx & 7) * 8;
      __builtin_amdgcn_global_load_lds(
          (const __attribute__((address_space(1))) void*)(ag + (size_t)row * 768 + kc),
          (__attribute__((address_space(3))) void*)(&As[idx * 8]), 16, 0, 0);
    }
#pragma unroll
    for (int i = 0; i < 4; ++i) {
      int idx = i * 256 + t;
      int row = idx >> 3;
      int kc = (idx & 7) * 8;
      __builtin_amdgcn_global_load_lds(
          (const __attribute__((address_space(1))) void*)(bg + (size_t)row * 768 + kc),
          (__attribute__((address_space(3))) void*)(&Bs[idx * 8]), 16, 0, 0);
    }
    __syncthreads();
#pragma unroll
    for (int kk = 0; kk < 2; ++kk) {
      bf16x8 af[4], bfv[4];
      int r = lane & 15, kc = kk * 32 + (lane >> 4) * 8;
#pragma unroll
      for (int mf = 0; mf < 4; ++mf)
        af[mf] = *(const bf16x8*)&As[(wm * 64 + mf * 16 + r) * 64 + kc];
#pragma unroll
      for (int nf = 0; nf < 4; ++nf)
        bfv[nf] = *(const bf16x8*)&Bs[(wn * 64 + nf * 16 + r) * 64 + kc];
#pragma unroll
      for (int mf = 0; mf < 4; ++mf)
#pragma unroll
        for (int nf = 0; nf < 4; ++nf)
          acc[mf][nf] = __builtin_amdgcn_mfma_f32_16x16x32_bf16(af[mf], bfv[nf], acc[mf][nf], 0, 0, 0);
    }
    __syncthreads();
  }
  float mu = st[b * 2], rstd = st[b * 2 + 1];
  __hip_bfloat16* out = kv + (size_t)b * 1536 * 1024;
#pragma unroll
  for (int mf = 0; mf < 4; ++mf) {
#pragma unroll
    for (int r = 0; r < 4; ++r) {
      int o = mt * 128 + wm * 64 + mf * 16 + (lane >> 4) * 4 + r;
      float corr = cst[o] - rstd * mu * rowsum[o];
#pragma unroll
      for (int nf = 0; nf < 4; ++nf) {
        int n = nt * 128 + wn * 64 + nf * 16 + (lane & 15);
        out[(size_t)o * 1024 + n] = __float2bfloat16(rstd * acc[mf][nf][r] + corr);
      }
    }
  }
}

// ---------------------------------------------------------------------------
// K5: q = LN(x_cls) @ Wq^T + bq   (per-batch block, o-tile 128)
__global__ __launch_bounds__(256) void q_proj(
    const float* __restrict__ x_cls, const float* __restrict__ lnw,
    const float* __restrict__ lnb, const float* __restrict__ WqT,
    const float* __restrict__ bq, float* __restrict__ Q) {
  __shared__ float xn[20 * 768];
  int b = blockIdx.x, ot = blockIdx.y;
  int t = threadIdx.x;
  const float* src = x_cls + (size_t)b * 20 * 768;
  for (int idx = t; idx < 15360; idx += 256) xn[idx] = src[idx];
  __syncthreads();
  int wid = t >> 6, lane = t & 63;
  for (int l = wid; l < 20; l += 4) {
    float s = 0.f;
#pragma unroll
    for (int i = 0; i < 12; ++i) s += xn[l * 768 + lane + i * 64];
#pragma unroll
    for (int o = 32; o > 0; o >>= 1) s += __shfl_down(s, o);
    s = __shfl(s, 0);
    float mu = s * (1.0f / 768.0f);
    float v = 0.f;
#pragma unroll
    for (int i = 0; i < 12; ++i) {
      float d = xn[l * 768 + lane + i * 64] - mu;
      v += d * d;
    }
#pragma unroll
    for (int o = 32; o > 0; o >>= 1) v += __shfl_down(v, o);
    v = __shfl(v, 0);
    float rstd = rsqrtf(v * (1.0f / 768.0f) + 1e-5f);
#pragma unroll
    for (int i = 0; i < 12; ++i) {
      int c = lane + i * 64;
      xn[l * 768 + c] = (xn[l * 768 + c] - mu) * rstd * lnw[c] + lnb[c];
    }
  }
  __syncthreads();
  int o = ot * 128 + (t & 127);
  int lg = t >> 7;
  float acc[10] = {};
  for (int c4 = 0; c4 < 768; c4 += 4) {
    float w0 = WqT[(size_t)(c4 + 0) * 768 + o];
    float w1 = WqT[(size_t)(c4 + 1) * 768 + o];
    float w2 = WqT[(size_t)(c4 + 2) * 768 + o];
    float w3 = WqT[(size_t)(c4 + 3) * 768 + o];
#pragma unroll
    for (int j = 0; j < 10; ++j) {
      const float4 a4 = *(const float4*)&xn[(lg * 10 + j) * 768 + c4];
      acc[j] += a4.x * w0 + a4.y * w1 + a4.z * w2 + a4.w * w3;
    }
  }
  float bqo = bq[o];
#pragma unroll
  for (int j = 0; j < 10; ++j)
    Q[((size_t)b * 20 + lg * 10 + j) * 768 + o] = acc[j] + bqo;
}

// ---------------------------------------------------------------------------
// K6: attention per (b,h): QK^T -> softmax -> PV
__global__ __launch_bounds__(1024) void attn_kernel(
    const float* __restrict__ Q, const __hip_bfloat16* __restrict__ kv,
    float* __restrict__ AO) {
  __shared__ float ql[20 * 192];
  __shared__ float sc[20][1024];
  __shared__ float rsum[20];
  __shared__ __hip_bfloat16 vch[192 * 68];
  int b = blockIdx.x >> 2, h = blockIdx.x & 3;
  int t = threadIdx.x;
  for (int idx = t; idx < 3840; idx += 1024) {
    int l = idx / 192, d = idx % 192;
    ql[idx] = Q[((size_t)b * 20 + l) * 768 + h * 192 + d];
  }
  __syncthreads();
  // QK^T: thread t owns column n=t
  const __hip_bfloat16* kbase = kv + ((size_t)b * 1536 + h * 192) * 1024;
  {
    int n = t;
    float acc20[20] = {};
    const __hip_bfloat16* kcol = kbase + n;
    for (int d4 = 0; d4 < 192; d4 += 4) {
      float k0 = __bfloat162float(kcol[(size_t)(d4 + 0) * 1024]);
      float k1 = __bfloat162float(kcol[(size_t)(d4 + 1) * 1024]);
      float k2 = __bfloat162float(kcol[(size_t)(d4 + 2) * 1024]);
      float k3 = __bfloat162float(kcol[(size_t)(d4 + 3) * 1024]);
#pragma unroll
      for (int l = 0; l < 20; ++l) {
        const float4 qv = *(const float4*)&ql[l * 192 + d4];
        acc20[l] += qv.x * k0 + qv.y * k1 + qv.z * k2 + qv.w * k3;
      }
    }
    const float scale = 0.07216878364870322f;
#pragma unroll
    for (int l = 0; l < 20; ++l) sc[l][n] = acc20[l] * scale;
  }
  __syncthreads();
  // softmax rows (keep exp, divide at end)
  int wid = t >> 6, lane = t & 63;
  for (int l = wid; l < 20; l += 16) {
    float m = -1e30f;
#pragma unroll
    for (int i = 0; i < 16; ++i) m = fmaxf(m, sc[l][lane + i * 64]);
#pragma unroll
    for (int o = 32; o > 0; o >>= 1) m = fmaxf(m, __shfl_down(m, o));
    m = __shfl(m, 0);
    float s = 0.f;
#pragma unroll
    for (int i = 0; i < 16; ++i) {
      float e = __expf(sc[l][lane + i * 64] - m);
      sc[l][lane + i * 64] = e;
      s += e;
    }
#pragma unroll
    for (int o = 32; o > 0; o >>= 1) s += __shfl_down(s, o);
    if (lane == 0) rsum[l] = s;
  }
  __syncthreads();
  // PV: 960 active threads, d = t%192, group g = t/192 owns rows g*4..g*4+3
  const __hip_bfloat16* vbase = kv + ((size_t)b * 1536 + 768 + h * 192) * 1024;
  int d = t % 192, g = t / 192;
  bool active = (t < 960);
  float acc[4] = {0.f, 0.f, 0.f, 0.f};
  for (int ch = 0; ch < 16; ++ch) {
    int n0 = ch * 64;
    for (int idx = t; idx < 12288; idx += 1024) {
      int dd = idx >> 6, nn = idx & 63;
      vch[dd * 68 + nn] = vbase[(size_t)dd * 1024 + n0 + nn];
    }
    __syncthreads();
    if (active) {
#pragma unroll
      for (int nn4 = 0; nn4 < 64; nn4 += 4) {
        bf16x4 vv = *(const bf16x4*)&vch[d * 68 + nn4];
        float v0 = (float)vv[0], v1 = (float)vv[1], v2 = (float)vv[2], v3 = (float)vv[3];
#pragma unroll
        for (int j = 0; j < 4; ++j) {
          const float4 sv = *(const float4*)&sc[g * 4 + j][n0 + nn4];
          acc[j] += sv.x * v0 + sv.y * v1 + sv.z * v2 + sv.w * v3;
        }
      }
    }
    __syncthreads();
  }
  if (active) {
#pragma unroll
    for (int j = 0; j < 4; ++j) {
      int l = g * 4 + j;
      AO[((size_t)b * 20 + l) * 768 + h * 192 + d] = acc[j] / rsum[l];
    }
  }
}

// ---------------------------------------------------------------------------
// K7: out_cls = x_cls + AO @ Wp^T + bp  -> d_out[0:245760]
__global__ __launch_bounds__(256) void cls_proj(
    const float* __restrict__ AO, const float* __restrict__ x_cls,
    const float* __restrict__ WpT, const float* __restrict__ bp,
    float* __restrict__ out_cls) {
  __shared__ float a[20 * 768];
  int b = blockIdx.x, ot = blockIdx.y;
  int t = threadIdx.x;
  const float* src = AO + (size_t)b * 15360;
  for (int idx = t; idx < 15360; idx += 256) a[idx] = src[idx];
  __syncthreads();
  int o = ot * 128 + (t & 127);
  int lg = t >> 7;
  float acc[10] = {};
  for (int c4 = 0; c4 < 768; c4 += 4) {
    float w0 = WpT[(size_t)(c4 + 0) * 768 + o];
    float w1 = WpT[(size_t)(c4 + 1) * 768 + o];
    float w2 = WpT[(size_t)(c4 + 2) * 768 + o];
    float w3 = WpT[(size_t)(c4 + 3) * 768 + o];
#pragma unroll
    for (int j = 0; j < 10; ++j) {
      const float4 a4 = *(const float4*)&a[(lg * 10 + j) * 768 + c4];
      acc[j] += a4.x * w0 + a4.y * w1 + a4.z * w2 + a4.w * w3;
    }
  }
  float bpo = bp[o];
#pragma unroll
  for (int j = 0; j < 10; ++j) {
    int l = lg * 10 + j;
    out_cls[((size_t)b * 20 + l) * 768 + o] =
        x_cls[((size_t)b * 20 + l) * 768 + o] + acc[j] + bpo;
  }
}

// ---------------------------------------------------------------------------
// K8: out_patch[b][l][n] = sum_c out_cls[b][l][c] * x[b][c][n]
__global__ __launch_bounds__(256) void patch_mm(
    const float* __restrict__ out_cls, const float* __restrict__ x,
    float* __restrict__ OP) {
  __shared__ float a[20 * 768];
  int b = blockIdx.x, nt2 = blockIdx.y;
  int t = threadIdx.x;
  const float* src = out_cls + (size_t)b * 15360;
  for (int idx = t; idx < 15360; idx += 256) a[idx] = src[idx];
  __syncthreads();
  int n = nt2 * 128 + (t & 127);
  int lg = t >> 7;
  const float* xb = x + (size_t)b * 768 * 1024 + n;
  float acc[10] = {};
  for (int c4 = 0; c4 < 768; c4 += 4) {
    float x0 = xb[(size_t)(c4 + 0) * 1024];
    float x1 = xb[(size_t)(c4 + 1) * 1024];
    float x2 = xb[(size_t)(c4 + 2) * 1024];
    float x3 = xb[(size_t)(c4 + 3) * 1024];
#pragma unroll
    for (int j = 0; j < 10; ++j) {
      const float4 a4 = *(const float4*)&a[(lg * 10 + j) * 768 + c4];
      acc[j] += a4.x * x0 + a4.y * x1 + a4.z * x2 + a4.w * x3;
    }
  }
#pragma unroll
  for (int j = 0; j < 10; ++j)
    OP[((size_t)b * 20 + lg * 10 + j) * 1024 + n] = acc[j];
}

// ---------------------------------------------------------------------------
// K9: 3x3 SAME conv (ic=20) + bias + BN + exact GELU -> y
__global__ __launch_bounds__(256) void conv_bn_gelu(
    const float* __restrict__ OP, const float* __restrict__ Wc,
    const float* __restrict__ bc, const float* __restrict__ bng,
    const float* __restrict__ bnb, const float* __restrict__ bnm,
    const float* __restrict__ bnv, float* __restrict__ y) {
  __shared__ float wsm[64 * 240];  // [ocl][ic][12] (9 used, padded for b128)
  __shared__ float ps[20 * 320];   // [ic][10 rows][32]
  int b = blockIdx.x, ocb = blockIdx.y, sq = blockIdx.z;
  int t = threadIdx.x;
  const float* wsrc = Wc + (size_t)ocb * 64 * 180;
  for (int idx = t; idx < 11520; idx += 256) {
    int ocl = idx / 180, rem = idx % 180;
    int ic = rem / 9, k9 = rem % 9;
    wsm[ocl * 240 + ic * 12 + k9] = wsrc[idx];
  }
  const float* pb = OP + (size_t)b * 20 * 1024;
  int y0 = sq * 8;
  for (int idx = t; idx < 6400; idx += 256) {
    int ic = idx / 320, rem = idx % 320;
    int yy = rem >> 5, xx = rem & 31;
    int yg = y0 - 1 + yy;
    ps[idx] = (yg >= 0 && yg < 32) ? pb[ic * 1024 + yg * 32 + xx] : 0.0f;
  }
  __syncthreads();
  int yl = t >> 5, x = t & 31;
  float acc[64];
#pragma unroll
  for (int i = 0; i < 64; ++i) acc[i] = 0.0f;
  for (int ic = 0; ic < 20; ++ic) {
    const float* pr = &ps[ic * 320 + yl * 32];
    float p00 = (x > 0) ? pr[x - 1] : 0.f, p01 = pr[x], p02 = (x < 31) ? pr[x + 1] : 0.f;
    float p10 = (x > 0) ? pr[32 + x - 1] : 0.f, p11 = pr[32 + x], p12 = (x < 31) ? pr[32 + x + 1] : 0.f;
    float p20 = (x > 0) ? pr[64 + x - 1] : 0.f, p21 = pr[64 + x], p22 = (x < 31) ? pr[64 + x + 1] : 0.f;
#pragma unroll
    for (int ocl = 0; ocl < 64; ++ocl) {
      const float4 w0 = *(const float4*)&wsm[ocl * 240 + ic * 12];
      const float4 w1 = *(const float4*)&wsm[ocl * 240 + ic * 12 + 4];
      float w8 = wsm[ocl * 240 + ic * 12 + 8];
      acc[ocl] += w0.x * p00 + w0.y * p01 + w0.z * p02
                + w0.w * p10 + w1.x * p11 + w1.y * p12
                + w1.z * p20 + w1.w * p21 + w8 * p22;
    }
  }
  int sp = (y0 + yl) * 32 + x;
  float* yb = y + (size_t)b * 768 * 1024 + sp;
#pragma unroll 4
  for (int ocl = 0; ocl < 64; ++ocl) {
    int oc = ocb * 64 + ocl;
    float s = bng[oc] * rsqrtf(bnv[oc] + 1e-5f);
    float val = (acc[ocl] + bc[oc] - bnm[oc]) * s + bnb[oc];
    yb[(size_t)oc * 1024] = 0.5f * val * (1.0f + erff(val * 0.70710678118f));
  }
}

// ---------------------------------------------------------------------------
extern "C" void kernel_launch(void* const* d_in, const int* in_sizes, int n_in,
                              void* d_out, int out_size, void* d_ws, size_t ws_size,
                              hipStream_t stream) {
  (void)in_sizes; (void)n_in; (void)out_size; (void)ws_size;
  const float* x_cls = (const float*)d_in[0];
  const float* x     = (const float*)d_in[1];
  const float* lnw   = (const float*)d_in[2];
  const float* lnb   = (const float*)d_in[3];
  const float* nxw   = (const float*)d_in[4];
  const float* nxb   = (const float*)d_in[5];
  const float* Wq    = (const float*)d_in[6];
  const float* bq    = (const float*)d_in[7];
  const float* Wkv   = (const float*)d_in[8];
  const float* bkv   = (const float*)d_in[9];
  const float* Wp    = (const float*)d_in[10];
  const float* bp    = (const float*)d_in[11];
  const float* Wc    = (const float*)d_in[12];
  const float* bc    = (const float*)d_in[13];
  const float* bng   = (const float*)d_in[14];
  const float* bnb   = (const float*)d_in[15];
  const float* bnm   = (const float*)d_in[16];
  const float* bnv   = (const float*)d_in[17];

  char* w = (char*)d_ws;
  __hip_bfloat16* xT = (__hip_bfloat16*)(w + OFF_XT);
  __hip_bfloat16* kv = (__hip_bfloat16*)(w + OFF_KV);
  __hip_bfloat16* Wb = (__hip_bfloat16*)(w + OFF_WB);
  float* rs   = (float*)(w + OFF_RS);
  float* cst  = (float*)(w + OFF_CST);
  float* part = (float*)(w + OFF_PART);
  float* st   = (float*)(w + OFF_ST);
  float* WqT  = (float*)(w + OFF_WQT);
  float* WpT  = (float*)(w + OFF_WPT);
  float* Qb   = (float*)(w + OFF_Q);
  float* AO   = (float*)(w + OFF_AO);
  float* OP   = (float*)(w + OFF_OP);

  float* out_cls = (float*)d_out;
  float* y = out_cls + 245760;

  transpose_reduce<<<dim3(16, 12, 16), 256, 0, stream>>>(x, xT, part);
  finalize_stats<<<1, 64, 0, stream>>>(part, st);
  prep_wkv<<<384, 256, 0, stream>>>(Wkv, nxw, nxb, bkv, Wb, rs, cst);
  transpose_w<<<dim3(12, 12, 2), 256, 0, stream>>>(Wq, Wp, WqT, WpT);
  gemm_kv<<<1536, 256, 0, stream>>>(Wb, xT, rs, cst, st, kv);
  q_proj<<<dim3(16, 6), 256, 0, stream>>>(x_cls, lnw, lnb, WqT, bq, Qb);
  attn_kernel<<<64, 1024, 0, stream>>>(Qb, kv, AO);
  cls_proj<<<dim3(16, 6), 256, 0, stream>>>(AO, x_cls, WpT, bp, out_cls);
  patch_mm<<<dim3(16, 8), 256, 0, stream>>>(out_cls, x, OP);
  conv_bn_gelu<<<dim3(16, 12, 4), 256, 0, stream>>>(OP, Wc, bc, bng, bnb, bnm, bnv, y);
}

// Round 2
// 576.470 us; speedup vs baseline: 1.4778x; 1.4778x over previous
//
#include <hip/hip_runtime.h>
#include <hip/hip_bf16.h>
#include <math.h>

typedef float f32x4 __attribute__((ext_vector_type(4)));
typedef __bf16 bf16x8 __attribute__((ext_vector_type(8)));
typedef __bf16 bf16x4 __attribute__((ext_vector_type(4)));

// Problem constants
// B=16, C=768, CLS=20, HEADS=4, dh=192, N=1024 (32x32), 2C=1536

// Workspace layout (bytes), all 16B aligned. Total ~85.9 MB.
static constexpr size_t OFF_XT   = 0;            // bf16 [16][1024][768]  x transposed
static constexpr size_t OFF_KV   = 25165824;     // bf16 [16][1536][1024]
static constexpr size_t OFF_WB   = 75497472;     // bf16 [1536][768]  Wkv*nx_w
static constexpr size_t OFF_RS   = 77856768;     // f32  [1536] rowsum
static constexpr size_t OFF_CST  = 77862912;     // f32  [1536] const term
static constexpr size_t OFF_PART = 77869056;     // f32  [3072][2] partial sums
static constexpr size_t OFF_ST   = 77893632;     // f32  [16][2] mu,rstd
static constexpr size_t OFF_WQT  = 77893760;     // f32  [768][768]
static constexpr size_t OFF_WPT  = 80253056;     // f32  [768][768]
static constexpr size_t OFF_Q    = 82612352;     // f32  [16][20][768]
static constexpr size_t OFF_AO   = 83595392;     // f32  [16][20][768]
static constexpr size_t OFF_OP   = 84578432;     // f32  [16][20][1024]

// Conv buffers live inside the xT region (xT is dead after gemm_kv; all conv
// prep kernels are ordered after gemm_kv in the launch sequence).
static constexpr size_t OFF_B2   = OFF_XT;             // bf16 [16][1024][192] im2col
static constexpr size_t OFF_WCB  = OFF_XT + 6291456;   // bf16 [768][192]
static constexpr size_t OFF_SC   = OFF_XT + 6586368;   // f32  [768] bn scale
static constexpr size_t OFF_SH   = OFF_XT + 6589440;   // f32  [768] bn shift

// ---------------------------------------------------------------------------
// K1: x [b][c][n] f32 -> xT [b][n][c] bf16, plus per-block partial sum/sumsq
__global__ __launch_bounds__(256) void transpose_reduce(
    const float* __restrict__ x, __hip_bfloat16* __restrict__ xT,
    float* __restrict__ part) {
  __shared__ __hip_bfloat16 tile[64][66];
  __shared__ float red[4][2];
  int b = blockIdx.x, cb = blockIdx.y, nb = blockIdx.z;
  int t = threadIdx.x;
  const float* src = x + ((size_t)b * 768 + cb * 64) * 1024 + nb * 64;
  float s1 = 0.f, s2 = 0.f;
#pragma unroll
  for (int i = 0; i < 16; ++i) {
    int idx = i * 256 + t;
    int c = idx >> 6, n = idx & 63;
    float v = src[(size_t)c * 1024 + n];
    s1 += v; s2 += v * v;
    tile[c][n] = __float2bfloat16(v);
  }
#pragma unroll
  for (int o = 32; o > 0; o >>= 1) {
    s1 += __shfl_down(s1, o);
    s2 += __shfl_down(s2, o);
  }
  int wid = t >> 6, lane = t & 63;
  if (lane == 0) { red[wid][0] = s1; red[wid][1] = s2; }
  __syncthreads();
  if (t == 0) {
    float a = 0.f, bb = 0.f;
    for (int w = 0; w < 4; ++w) { a += red[w][0]; bb += red[w][1]; }
    int pidx = b * 192 + cb * 16 + nb;
    part[pidx * 2] = a; part[pidx * 2 + 1] = bb;
  }
  __hip_bfloat16* dst = xT + ((size_t)b * 1024 + nb * 64) * 768 + cb * 64;
#pragma unroll
  for (int i = 0; i < 16; ++i) {
    int idx = i * 256 + t;
    int n = idx >> 6, c = idx & 63;
    dst[(size_t)n * 768 + c] = tile[c][n];
  }
}

// ---------------------------------------------------------------------------
// K2: finalize per-batch mu / rstd
__global__ void finalize_stats(const float* __restrict__ part, float* __restrict__ st) {
  int t = threadIdx.x;
  if (t < 16) {
    float s1 = 0.f, s2 = 0.f;
    for (int i = 0; i < 192; ++i) {
      s1 += part[(t * 192 + i) * 2];
      s2 += part[(t * 192 + i) * 2 + 1];
    }
    float mu = s1 * (1.0f / 786432.0f);
    float var = s2 * (1.0f / 786432.0f) - mu * mu;
    st[t * 2] = mu;
    st[t * 2 + 1] = rsqrtf(var + 1e-5f);
  }
}

// ---------------------------------------------------------------------------
// K3: W' = Wkv * nx_w (bf16), rowsum = sum_c W', cst = sum_c Wkv*nx_b + bkv
__global__ __launch_bounds__(256) void prep_wkv(
    const float* __restrict__ Wkv, const float* __restrict__ nxw,
    const float* __restrict__ nxb, const float* __restrict__ bkv,
    __hip_bfloat16* __restrict__ Wb, float* __restrict__ rowsum,
    float* __restrict__ cst) {
  int o = blockIdx.x * 4 + (threadIdx.x >> 6);
  int lane = threadIdx.x & 63;
  const float* wrow = Wkv + (size_t)o * 768;
  float rs = 0.f, cs = 0.f;
#pragma unroll
  for (int i = 0; i < 12; ++i) {
    int c = lane + i * 64;
    float w = wrow[c];
    float wb = w * nxw[c];
    Wb[(size_t)o * 768 + c] = __float2bfloat16(wb);
    rs += wb;
    cs += w * nxb[c];
  }
#pragma unroll
  for (int off = 32; off > 0; off >>= 1) {
    rs += __shfl_down(rs, off);
    cs += __shfl_down(cs, off);
  }
  if (lane == 0) { rowsum[o] = rs; cst[o] = cs + bkv[o]; }
}

// ---------------------------------------------------------------------------
// K3b: transpose Wq, Wp -> WqT, WpT (f32)
__global__ __launch_bounds__(256) void transpose_w(
    const float* __restrict__ Wq, const float* __restrict__ Wp,
    float* __restrict__ WqT, float* __restrict__ WpT) {
  __shared__ float tl[64][65];
  const float* src = blockIdx.z ? Wp : Wq;
  float* dst = blockIdx.z ? WpT : WqT;
  int ot = blockIdx.x * 64, ct = blockIdx.y * 64;
  int t = threadIdx.x;
#pragma unroll
  for (int i = 0; i < 16; ++i) {
    int idx = i * 256 + t;
    int o = idx >> 6, c = idx & 63;
    tl[o][c] = src[(size_t)(ot + o) * 768 + ct + c];
  }
  __syncthreads();
#pragma unroll
  for (int i = 0; i < 16; ++i) {
    int idx = i * 256 + t;
    int c = idx >> 6, o = idx & 63;
    dst[(size_t)(ct + c) * 768 + ot + o] = tl[o][c];
  }
}

// ---------------------------------------------------------------------------
// K4: kv = rstd*(W' @ x) + (cst - rstd*mu*rowsum), bf16 MFMA, 128x128 tile
__global__ __launch_bounds__(256) void gemm_kv(
    const __hip_bfloat16* __restrict__ Wb, const __hip_bfloat16* __restrict__ xT,
    const float* __restrict__ rowsum, const float* __restrict__ cst,
    const float* __restrict__ st, __hip_bfloat16* __restrict__ kv) {
  __shared__ __hip_bfloat16 As[128 * 64];
  __shared__ __hip_bfloat16 Bs[128 * 64];
  int gx = blockIdx.x;                       // 1536 blocks
  int wg = (gx & 7) * 192 + (gx >> 3);       // bijective XCD swizzle (1536 % 8 == 0)
  int mt = wg % 12;
  int colt = wg / 12;                        // 0..127
  int b = colt >> 3;
  int nt = colt & 7;
  int t = threadIdx.x;
  int wid = t >> 6, lane = t & 63;
  int wm = wid >> 1, wn = wid & 1;

  const __hip_bfloat16* Abase = Wb + (size_t)(mt * 128) * 768;
  const __hip_bfloat16* Bbase = xT + (size_t)b * 1024 * 768 + (size_t)(nt * 128) * 768;

  f32x4 acc[4][4] = {};

  for (int kt = 0; kt < 12; ++kt) {
    const __hip_bfloat16* ag = Abase + kt * 64;
    const __hip_bfloat16* bg = Bbase + kt * 64;
#pragma unroll
    for (int i = 0; i < 4; ++i) {
      int idx = i * 256 + t;
      int row = idx >> 3;
      int kc = (idx & 7) * 8;
      __builtin_amdgcn_global_load_lds(
          (const __attribute__((address_space(1))) void*)(ag + (size_t)row * 768 + kc),
          (__attribute__((address_space(3))) void*)(&As[idx * 8]), 16, 0, 0);
    }
#pragma unroll
    for (int i = 0; i < 4; ++i) {
      int idx = i * 256 + t;
      int row = idx >> 3;
      int kc = (idx & 7) * 8;
      __builtin_amdgcn_global_load_lds(
          (const __attribute__((address_space(1))) void*)(bg + (size_t)row * 768 + kc),
          (__attribute__((address_space(3))) void*)(&Bs[idx * 8]), 16, 0, 0);
    }
    __syncthreads();
#pragma unroll
    for (int kk = 0; kk < 2; ++kk) {
      bf16x8 af[4], bfv[4];
      int r = lane & 15, kc = kk * 32 + (lane >> 4) * 8;
#pragma unroll
      for (int mf = 0; mf < 4; ++mf)
        af[mf] = *(const bf16x8*)&As[(wm * 64 + mf * 16 + r) * 64 + kc];
#pragma unroll
      for (int nf = 0; nf < 4; ++nf)
        bfv[nf] = *(const bf16x8*)&Bs[(wn * 64 + nf * 16 + r) * 64 + kc];
#pragma unroll
      for (int mf = 0; mf < 4; ++mf)
#pragma unroll
        for (int nf = 0; nf < 4; ++nf)
          acc[mf][nf] = __builtin_amdgcn_mfma_f32_16x16x32_bf16(af[mf], bfv[nf], acc[mf][nf], 0, 0, 0);
    }
    __syncthreads();
  }
  float mu = st[b * 2], rstd = st[b * 2 + 1];
  __hip_bfloat16* out = kv + (size_t)b * 1536 * 1024;
#pragma unroll
  for (int mf = 0; mf < 4; ++mf) {
#pragma unroll
    for (int r = 0; r < 4; ++r) {
      int o = mt * 128 + wm * 64 + mf * 16 + (lane >> 4) * 4 + r;
      float corr = cst[o] - rstd * mu * rowsum[o];
#pragma unroll
      for (int nf = 0; nf < 4; ++nf) {
        int n = nt * 128 + wn * 64 + nf * 16 + (lane & 15);
        out[(size_t)o * 1024 + n] = __float2bfloat16(rstd * acc[mf][nf][r] + corr);
      }
    }
  }
}

// ---------------------------------------------------------------------------
// K5: q = LN(x_cls) @ Wq^T + bq   (per-batch block, o-tile 128)
__global__ __launch_bounds__(256) void q_proj(
    const float* __restrict__ x_cls, const float* __restrict__ lnw,
    const float* __restrict__ lnb, const float* __restrict__ WqT,
    const float* __restrict__ bq, float* __restrict__ Q) {
  __shared__ float xn[20 * 768];
  int b = blockIdx.x, ot = blockIdx.y;
  int t = threadIdx.x;
  const float* src = x_cls + (size_t)b * 20 * 768;
  for (int idx = t; idx < 15360; idx += 256) xn[idx] = src[idx];
  __syncthreads();
  int wid = t >> 6, lane = t & 63;
  for (int l = wid; l < 20; l += 4) {
    float s = 0.f;
#pragma unroll
    for (int i = 0; i < 12; ++i) s += xn[l * 768 + lane + i * 64];
#pragma unroll
    for (int o = 32; o > 0; o >>= 1) s += __shfl_down(s, o);
    s = __shfl(s, 0);
    float mu = s * (1.0f / 768.0f);
    float v = 0.f;
#pragma unroll
    for (int i = 0; i < 12; ++i) {
      float d = xn[l * 768 + lane + i * 64] - mu;
      v += d * d;
    }
#pragma unroll
    for (int o = 32; o > 0; o >>= 1) v += __shfl_down(v, o);
    v = __shfl(v, 0);
    float rstd = rsqrtf(v * (1.0f / 768.0f) + 1e-5f);
#pragma unroll
    for (int i = 0; i < 12; ++i) {
      int c = lane + i * 64;
      xn[l * 768 + c] = (xn[l * 768 + c] - mu) * rstd * lnw[c] + lnb[c];
    }
  }
  __syncthreads();
  int o = ot * 128 + (t & 127);
  int lg = t >> 7;
  float acc[10] = {};
  for (int c4 = 0; c4 < 768; c4 += 4) {
    float w0 = WqT[(size_t)(c4 + 0) * 768 + o];
    float w1 = WqT[(size_t)(c4 + 1) * 768 + o];
    float w2 = WqT[(size_t)(c4 + 2) * 768 + o];
    float w3 = WqT[(size_t)(c4 + 3) * 768 + o];
#pragma unroll
    for (int j = 0; j < 10; ++j) {
      const float4 a4 = *(const float4*)&xn[(lg * 10 + j) * 768 + c4];
      acc[j] += a4.x * w0 + a4.y * w1 + a4.z * w2 + a4.w * w3;
    }
  }
  float bqo = bq[o];
#pragma unroll
  for (int j = 0; j < 10; ++j)
    Q[((size_t)b * 20 + lg * 10 + j) * 768 + o] = acc[j] + bqo;
}

// ---------------------------------------------------------------------------
// K6: attention per (b,h): QK^T -> softmax -> PV
__global__ __launch_bounds__(1024) void attn_kernel(
    const float* __restrict__ Q, const __hip_bfloat16* __restrict__ kv,
    float* __restrict__ AO) {
  __shared__ float ql[20 * 192];
  __shared__ float sc[20][1024];
  __shared__ float rsum[20];
  __shared__ __hip_bfloat16 vch[192 * 68];
  int b = blockIdx.x >> 2, h = blockIdx.x & 3;
  int t = threadIdx.x;
  for (int idx = t; idx < 3840; idx += 1024) {
    int l = idx / 192, d = idx % 192;
    ql[idx] = Q[((size_t)b * 20 + l) * 768 + h * 192 + d];
  }
  __syncthreads();
  // QK^T: thread t owns column n=t
  const __hip_bfloat16* kbase = kv + ((size_t)b * 1536 + h * 192) * 1024;
  {
    int n = t;
    float acc20[20] = {};
    const __hip_bfloat16* kcol = kbase + n;
    for (int d4 = 0; d4 < 192; d4 += 4) {
      float k0 = __bfloat162float(kcol[(size_t)(d4 + 0) * 1024]);
      float k1 = __bfloat162float(kcol[(size_t)(d4 + 1) * 1024]);
      float k2 = __bfloat162float(kcol[(size_t)(d4 + 2) * 1024]);
      float k3 = __bfloat162float(kcol[(size_t)(d4 + 3) * 1024]);
#pragma unroll
      for (int l = 0; l < 20; ++l) {
        const float4 qv = *(const float4*)&ql[l * 192 + d4];
        acc20[l] += qv.x * k0 + qv.y * k1 + qv.z * k2 + qv.w * k3;
      }
    }
    const float scale = 0.07216878364870322f;
#pragma unroll
    for (int l = 0; l < 20; ++l) sc[l][n] = acc20[l] * scale;
  }
  __syncthreads();
  // softmax rows (keep exp, divide at end)
  int wid = t >> 6, lane = t & 63;
  for (int l = wid; l < 20; l += 16) {
    float m = -1e30f;
#pragma unroll
    for (int i = 0; i < 16; ++i) m = fmaxf(m, sc[l][lane + i * 64]);
#pragma unroll
    for (int o = 32; o > 0; o >>= 1) m = fmaxf(m, __shfl_down(m, o));
    m = __shfl(m, 0);
    float s = 0.f;
#pragma unroll
    for (int i = 0; i < 16; ++i) {
      float e = __expf(sc[l][lane + i * 64] - m);
      sc[l][lane + i * 64] = e;
      s += e;
    }
#pragma unroll
    for (int o = 32; o > 0; o >>= 1) s += __shfl_down(s, o);
    if (lane == 0) rsum[l] = s;
  }
  __syncthreads();
  // PV: 960 active threads, d = t%192, group g = t/192 owns rows g*4..g*4+3
  const __hip_bfloat16* vbase = kv + ((size_t)b * 1536 + 768 + h * 192) * 1024;
  int d = t % 192, g = t / 192;
  bool active = (t < 960);
  float acc[4] = {0.f, 0.f, 0.f, 0.f};
  for (int ch = 0; ch < 16; ++ch) {
    int n0 = ch * 64;
    for (int idx = t; idx < 12288; idx += 1024) {
      int dd = idx >> 6, nn = idx & 63;
      vch[dd * 68 + nn] = vbase[(size_t)dd * 1024 + n0 + nn];
    }
    __syncthreads();
    if (active) {
#pragma unroll
      for (int nn4 = 0; nn4 < 64; nn4 += 4) {
        bf16x4 vv = *(const bf16x4*)&vch[d * 68 + nn4];
        float v0 = (float)vv[0], v1 = (float)vv[1], v2 = (float)vv[2], v3 = (float)vv[3];
#pragma unroll
        for (int j = 0; j < 4; ++j) {
          const float4 sv = *(const float4*)&sc[g * 4 + j][n0 + nn4];
          acc[j] += sv.x * v0 + sv.y * v1 + sv.z * v2 + sv.w * v3;
        }
      }
    }
    __syncthreads();
  }
  if (active) {
#pragma unroll
    for (int j = 0; j < 4; ++j) {
      int l = g * 4 + j;
      AO[((size_t)b * 20 + l) * 768 + h * 192 + d] = acc[j] / rsum[l];
    }
  }
}

// ---------------------------------------------------------------------------
// K7: out_cls = x_cls + AO @ Wp^T + bp  -> d_out[0:245760]
__global__ __launch_bounds__(256) void cls_proj(
    const float* __restrict__ AO, const float* __restrict__ x_cls,
    const float* __restrict__ WpT, const float* __restrict__ bp,
    float* __restrict__ out_cls) {
  __shared__ float a[20 * 768];
  int b = blockIdx.x, ot = blockIdx.y;
  int t = threadIdx.x;
  const float* src = AO + (size_t)b * 15360;
  for (int idx = t; idx < 15360; idx += 256) a[idx] = src[idx];
  __syncthreads();
  int o = ot * 128 + (t & 127);
  int lg = t >> 7;
  float acc[10] = {};
  for (int c4 = 0; c4 < 768; c4 += 4) {
    float w0 = WpT[(size_t)(c4 + 0) * 768 + o];
    float w1 = WpT[(size_t)(c4 + 1) * 768 + o];
    float w2 = WpT[(size_t)(c4 + 2) * 768 + o];
    float w3 = WpT[(size_t)(c4 + 3) * 768 + o];
#pragma unroll
    for (int j = 0; j < 10; ++j) {
      const float4 a4 = *(const float4*)&a[(lg * 10 + j) * 768 + c4];
      acc[j] += a4.x * w0 + a4.y * w1 + a4.z * w2 + a4.w * w3;
    }
  }
  float bpo = bp[o];
#pragma unroll
  for (int j = 0; j < 10; ++j) {
    int l = lg * 10 + j;
    out_cls[((size_t)b * 20 + l) * 768 + o] =
        x_cls[((size_t)b * 20 + l) * 768 + o] + acc[j] + bpo;
  }
}

// ---------------------------------------------------------------------------
// K8: out_patch[b][l][n] = sum_c out_cls[b][l][c] * x[b][c][n]
__global__ __launch_bounds__(256) void patch_mm(
    const float* __restrict__ out_cls, const float* __restrict__ x,
    float* __restrict__ OP) {
  __shared__ float a[20 * 768];
  int b = blockIdx.x, nt2 = blockIdx.y;
  int t = threadIdx.x;
  const float* src = out_cls + (size_t)b * 15360;
  for (int idx = t; idx < 15360; idx += 256) a[idx] = src[idx];
  __syncthreads();
  int n = nt2 * 128 + (t & 127);
  int lg = t >> 7;
  const float* xb = x + (size_t)b * 768 * 1024 + n;
  float acc[10] = {};
  for (int c4 = 0; c4 < 768; c4 += 4) {
    float x0 = xb[(size_t)(c4 + 0) * 1024];
    float x1 = xb[(size_t)(c4 + 1) * 1024];
    float x2 = xb[(size_t)(c4 + 2) * 1024];
    float x3 = xb[(size_t)(c4 + 3) * 1024];
#pragma unroll
    for (int j = 0; j < 10; ++j) {
      const float4 a4 = *(const float4*)&a[(lg * 10 + j) * 768 + c4];
      acc[j] += a4.x * x0 + a4.y * x1 + a4.z * x2 + a4.w * x3;
    }
  }
#pragma unroll
  for (int j = 0; j < 10; ++j)
    OP[((size_t)b * 20 + lg * 10 + j) * 1024 + n] = acc[j];
}

// ---------------------------------------------------------------------------
// K9a: conv weight prep: Wc [768][180] f32 -> Wcb [768][192] bf16 (zero-pad),
//      plus folded BN scale/shift per oc.
__global__ __launch_bounds__(192) void prep_wconv(
    const float* __restrict__ Wc, const float* __restrict__ bc,
    const float* __restrict__ bng, const float* __restrict__ bnb,
    const float* __restrict__ bnm, const float* __restrict__ bnv,
    __hip_bfloat16* __restrict__ Wcb, float* __restrict__ sc,
    float* __restrict__ sh) {
  int oc = blockIdx.x;
  int k = threadIdx.x;
  float v = (k < 180) ? Wc[(size_t)oc * 180 + k] : 0.0f;
  Wcb[(size_t)oc * 192 + k] = __float2bfloat16(v);
  if (k == 0) {
    float s = bng[oc] * rsqrtf(bnv[oc] + 1e-5f);
    sc[oc] = s;
    sh[oc] = (bc[oc] - bnm[oc]) * s + bnb[oc];
  }
}

// ---------------------------------------------------------------------------
// K9b: im2col: Bmat[b][n=(y,x)][k=(ic*9+kh*3+kw)] = OP[b][ic][y+kh-1][x+kw-1]
//      (0 when out of bounds or k>=180). bf16, K padded to 192.
__global__ __launch_bounds__(256) void im2col(
    const float* __restrict__ OP, __hip_bfloat16* __restrict__ Bm) {
  int idx = blockIdx.x * 256 + threadIdx.x;   // over 16*1024*96 pairs
  int b = idx / (1024 * 96);
  int r = idx % (1024 * 96);
  int n = r / 96;
  int kp = (r % 96) * 2;
  int y = n >> 5, x = n & 31;
  const float* pb = OP + (size_t)b * 20 * 1024;
  float v[2];
#pragma unroll
  for (int j = 0; j < 2; ++j) {
    int k = kp + j;
    float val = 0.0f;
    if (k < 180) {
      int ic = k / 9, k9 = k % 9;
      int kh = k9 / 3, kw = k9 % 3;
      int yy = y + kh - 1, xx = x + kw - 1;
      if (yy >= 0 && yy < 32 && xx >= 0 && xx < 32)
        val = pb[ic * 1024 + yy * 32 + xx];
    }
    v[j] = val;
  }
  __hip_bfloat162 o2;
  o2.x = __float2bfloat16(v[0]);
  o2.y = __float2bfloat16(v[1]);
  *(__hip_bfloat162*)&Bm[(size_t)idx * 2] = o2;
}

// ---------------------------------------------------------------------------
// K9c: implicit-GEMM conv: y = GELU(BN(Wcb @ Bmat^T)), M=768, N=16384, K=192
__global__ __launch_bounds__(256) void gemm_conv(
    const __hip_bfloat16* __restrict__ Wcb, const __hip_bfloat16* __restrict__ Bm,
    const float* __restrict__ sc, const float* __restrict__ sh,
    float* __restrict__ y) {
  __shared__ __hip_bfloat16 As[128 * 64];
  __shared__ __hip_bfloat16 Bs[128 * 64];
  int gx = blockIdx.x;                      // 768 blocks
  int wg = (gx & 7) * 96 + (gx >> 3);       // bijective XCD swizzle (768 % 8 == 0)
  int mt = wg % 6;
  int colt = wg / 6;                        // 0..127
  int b = colt >> 3;
  int nt = colt & 7;
  int t = threadIdx.x;
  int wid = t >> 6, lane = t & 63;
  int wm = wid >> 1, wn = wid & 1;

  const __hip_bfloat16* Abase = Wcb + (size_t)(mt * 128) * 192;
  const __hip_bfloat16* Bbase = Bm + ((size_t)b * 1024 + nt * 128) * 192;

  f32x4 acc[4][4] = {};

  for (int kt = 0; kt < 3; ++kt) {
    const __hip_bfloat16* ag = Abase + kt * 64;
    const __hip_bfloat16* bg = Bbase + kt * 64;
#pragma unroll
    for (int i = 0; i < 4; ++i) {
      int idx = i * 256 + t;
      int row = idx >> 3;
      int kc = (idx & 7) * 8;
      __builtin_amdgcn_global_load_lds(
          (const __attribute__((address_space(1))) void*)(ag + (size_t)row * 192 + kc),
          (__attribute__((address_space(3))) void*)(&As[idx * 8]), 16, 0, 0);
    }
#pragma unroll
    for (int i = 0; i < 4; ++i) {
      int idx = i * 256 + t;
      int row = idx >> 3;
      int kc = (idx & 7) * 8;
      __builtin_amdgcn_global_load_lds(
          (const __attribute__((address_space(1))) void*)(bg + (size_t)row * 192 + kc),
          (__attribute__((address_space(3))) void*)(&Bs[idx * 8]), 16, 0, 0);
    }
    __syncthreads();
#pragma unroll
    for (int kk = 0; kk < 2; ++kk) {
      bf16x8 af[4], bfv[4];
      int r = lane & 15, kc = kk * 32 + (lane >> 4) * 8;
#pragma unroll
      for (int mf = 0; mf < 4; ++mf)
        af[mf] = *(const bf16x8*)&As[(wm * 64 + mf * 16 + r) * 64 + kc];
#pragma unroll
      for (int nf = 0; nf < 4; ++nf)
        bfv[nf] = *(const bf16x8*)&Bs[(wn * 64 + nf * 16 + r) * 64 + kc];
#pragma unroll
      for (int mf = 0; mf < 4; ++mf)
#pragma unroll
        for (int nf = 0; nf < 4; ++nf)
          acc[mf][nf] = __builtin_amdgcn_mfma_f32_16x16x32_bf16(af[mf], bfv[nf], acc[mf][nf], 0, 0, 0);
    }
    __syncthreads();
  }
  float* yb = y + (size_t)b * 768 * 1024;
#pragma unroll
  for (int mf = 0; mf < 4; ++mf) {
#pragma unroll
    for (int r = 0; r < 4; ++r) {
      int oc = mt * 128 + wm * 64 + mf * 16 + (lane >> 4) * 4 + r;
      float s = sc[oc], h = sh[oc];
#pragma unroll
      for (int nf = 0; nf < 4; ++nf) {
        int n = nt * 128 + wn * 64 + nf * 16 + (lane & 15);
        float val = acc[mf][nf][r] * s + h;
        yb[(size_t)oc * 1024 + n] = 0.5f * val * (1.0f + erff(val * 0.70710678118f));
      }
    }
  }
}

// ---------------------------------------------------------------------------
extern "C" void kernel_launch(void* const* d_in, const int* in_sizes, int n_in,
                              void* d_out, int out_size, void* d_ws, size_t ws_size,
                              hipStream_t stream) {
  (void)in_sizes; (void)n_in; (void)out_size; (void)ws_size;
  const float* x_cls = (const float*)d_in[0];
  const float* x     = (const float*)d_in[1];
  const float* lnw   = (const float*)d_in[2];
  const float* lnb   = (const float*)d_in[3];
  const float* nxw   = (const float*)d_in[4];
  const float* nxb   = (const float*)d_in[5];
  const float* Wq    = (const float*)d_in[6];
  const float* bq    = (const float*)d_in[7];
  const float* Wkv   = (const float*)d_in[8];
  const float* bkv   = (const float*)d_in[9];
  const float* Wp    = (const float*)d_in[10];
  const float* bp    = (const float*)d_in[11];
  const float* Wc    = (const float*)d_in[12];
  const float* bc    = (const float*)d_in[13];
  const float* bng   = (const float*)d_in[14];
  const float* bnb   = (const float*)d_in[15];
  const float* bnm   = (const float*)d_in[16];
  const float* bnv   = (const float*)d_in[17];

  char* w = (char*)d_ws;
  __hip_bfloat16* xT = (__hip_bfloat16*)(w + OFF_XT);
  __hip_bfloat16* kv = (__hip_bfloat16*)(w + OFF_KV);
  __hip_bfloat16* Wb = (__hip_bfloat16*)(w + OFF_WB);
  float* rs   = (float*)(w + OFF_RS);
  float* cst  = (float*)(w + OFF_CST);
  float* part = (float*)(w + OFF_PART);
  float* st   = (float*)(w + OFF_ST);
  float* WqT  = (float*)(w + OFF_WQT);
  float* WpT  = (float*)(w + OFF_WPT);
  float* Qb   = (float*)(w + OFF_Q);
  float* AO   = (float*)(w + OFF_AO);
  float* OP   = (float*)(w + OFF_OP);
  __hip_bfloat16* Bm  = (__hip_bfloat16*)(w + OFF_B2);
  __hip_bfloat16* Wcb = (__hip_bfloat16*)(w + OFF_WCB);
  float* scb  = (float*)(w + OFF_SC);
  float* shb  = (float*)(w + OFF_SH);

  float* out_cls = (float*)d_out;
  float* y = out_cls + 245760;

  transpose_reduce<<<dim3(16, 12, 16), 256, 0, stream>>>(x, xT, part);
  finalize_stats<<<1, 64, 0, stream>>>(part, st);
  prep_wkv<<<384, 256, 0, stream>>>(Wkv, nxw, nxb, bkv, Wb, rs, cst);
  transpose_w<<<dim3(12, 12, 2), 256, 0, stream>>>(Wq, Wp, WqT, WpT);
  gemm_kv<<<1536, 256, 0, stream>>>(Wb, xT, rs, cst, st, kv);
  // conv weight prep (writes into xT region -> must come after gemm_kv)
  prep_wconv<<<768, 192, 0, stream>>>(Wc, bc, bng, bnb, bnm, bnv, Wcb, scb, shb);
  q_proj<<<dim3(16, 6), 256, 0, stream>>>(x_cls, lnw, lnb, WqT, bq, Qb);
  attn_kernel<<<64, 1024, 0, stream>>>(Qb, kv, AO);
  cls_proj<<<dim3(16, 6), 256, 0, stream>>>(AO, x_cls, WpT, bp, out_cls);
  patch_mm<<<dim3(16, 8), 256, 0, stream>>>(out_cls, x, OP);
  im2col<<<6144, 256, 0, stream>>>(OP, Bm);
  gemm_conv<<<768, 256, 0, stream>>>(Wcb, Bm, scb, shb, y);
}

// Round 3
// 456.812 us; speedup vs baseline: 1.8649x; 1.2619x over previous
//
#include <hip/hip_runtime.h>
#include <hip/hip_bf16.h>
#include <math.h>

typedef float f32x4 __attribute__((ext_vector_type(4)));
typedef __bf16 bf16x8 __attribute__((ext_vector_type(8)));
typedef __bf16 bf16x4 __attribute__((ext_vector_type(4)));

// Problem constants
// B=16, C=768, CLS=20, HEADS=4, dh=192, N=1024 (32x32), 2C=1536

// Workspace layout (bytes), all 16B aligned. Total ~85.9 MB.
static constexpr size_t OFF_XT   = 0;            // bf16 [16][1024][768]  x transposed
static constexpr size_t OFF_KT   = 25165824;     // bf16 [16][1024][768]  K transposed
static constexpr size_t OFF_V    = 50331648;     // bf16 [16][768][1024]  V
static constexpr size_t OFF_WB   = 75497472;     // bf16 [1536][768]  Wkv*nx_w
static constexpr size_t OFF_RS   = 77856768;     // f32  [1536] rowsum
static constexpr size_t OFF_CST  = 77862912;     // f32  [1536] const term
static constexpr size_t OFF_PART = 77869056;     // f32  [3072][2] partial sums
static constexpr size_t OFF_ST   = 77893632;     // f32  [16][2] mu,rstd
static constexpr size_t OFF_WQT  = 77893760;     // f32  [768][768]
static constexpr size_t OFF_WPT  = 80253056;     // f32  [768][768]
static constexpr size_t OFF_Q    = 82612352;     // bf16 [16][20][768]
static constexpr size_t OFF_AO   = 83595392;     // f32  [16][20][768]
static constexpr size_t OFF_OP   = 84578432;     // f32  [16][20][1024]

// Conv buffers live inside the xT region (xT is dead after gemm_kv; im2col /
// gemm_conv are ordered after attention in the launch sequence).
static constexpr size_t OFF_B2   = OFF_XT;             // bf16 [16][1024][192] im2col
static constexpr size_t OFF_WCB  = OFF_XT + 6291456;   // bf16 [768][192]
static constexpr size_t OFF_SC   = OFF_XT + 6586368;   // f32  [768] bn scale
static constexpr size_t OFF_SH   = OFF_XT + 6589440;   // f32  [768] bn shift

// ---------------------------------------------------------------------------
// K1: x [b][c][n] f32 -> xT [b][n][c] bf16, plus per-block partial sum/sumsq
__global__ __launch_bounds__(256) void transpose_reduce(
    const float* __restrict__ x, __hip_bfloat16* __restrict__ xT,
    float* __restrict__ part) {
  __shared__ __hip_bfloat16 tile[64][66];
  __shared__ float red[4][2];
  int b = blockIdx.x, cb = blockIdx.y, nb = blockIdx.z;
  int t = threadIdx.x;
  const float* src = x + ((size_t)b * 768 + cb * 64) * 1024 + nb * 64;
  float s1 = 0.f, s2 = 0.f;
#pragma unroll
  for (int i = 0; i < 16; ++i) {
    int idx = i * 256 + t;
    int c = idx >> 6, n = idx & 63;
    float v = src[(size_t)c * 1024 + n];
    s1 += v; s2 += v * v;
    tile[c][n] = __float2bfloat16(v);
  }
#pragma unroll
  for (int o = 32; o > 0; o >>= 1) {
    s1 += __shfl_down(s1, o);
    s2 += __shfl_down(s2, o);
  }
  int wid = t >> 6, lane = t & 63;
  if (lane == 0) { red[wid][0] = s1; red[wid][1] = s2; }
  __syncthreads();
  if (t == 0) {
    float a = 0.f, bb = 0.f;
    for (int w = 0; w < 4; ++w) { a += red[w][0]; bb += red[w][1]; }
    int pidx = b * 192 + cb * 16 + nb;
    part[pidx * 2] = a; part[pidx * 2 + 1] = bb;
  }
  __hip_bfloat16* dst = xT + ((size_t)b * 1024 + nb * 64) * 768 + cb * 64;
#pragma unroll
  for (int i = 0; i < 16; ++i) {
    int idx = i * 256 + t;
    int n = idx >> 6, c = idx & 63;
    dst[(size_t)n * 768 + c] = tile[c][n];
  }
}

// ---------------------------------------------------------------------------
// K2: finalize per-batch mu / rstd
__global__ void finalize_stats(const float* __restrict__ part, float* __restrict__ st) {
  int t = threadIdx.x;
  if (t < 16) {
    float s1 = 0.f, s2 = 0.f;
    for (int i = 0; i < 192; ++i) {
      s1 += part[(t * 192 + i) * 2];
      s2 += part[(t * 192 + i) * 2 + 1];
    }
    float mu = s1 * (1.0f / 786432.0f);
    float var = s2 * (1.0f / 786432.0f) - mu * mu;
    st[t * 2] = mu;
    st[t * 2 + 1] = rsqrtf(var + 1e-5f);
  }
}

// ---------------------------------------------------------------------------
// K3: W' = Wkv * nx_w (bf16), rowsum = sum_c W', cst = sum_c Wkv*nx_b + bkv
__global__ __launch_bounds__(256) void prep_wkv(
    const float* __restrict__ Wkv, const float* __restrict__ nxw,
    const float* __restrict__ nxb, const float* __restrict__ bkv,
    __hip_bfloat16* __restrict__ Wb, float* __restrict__ rowsum,
    float* __restrict__ cst) {
  int o = blockIdx.x * 4 + (threadIdx.x >> 6);
  int lane = threadIdx.x & 63;
  const float* wrow = Wkv + (size_t)o * 768;
  float rs = 0.f, cs = 0.f;
#pragma unroll
  for (int i = 0; i < 12; ++i) {
    int c = lane + i * 64;
    float w = wrow[c];
    float wb = w * nxw[c];
    Wb[(size_t)o * 768 + c] = __float2bfloat16(wb);
    rs += wb;
    cs += w * nxb[c];
  }
#pragma unroll
  for (int off = 32; off > 0; off >>= 1) {
    rs += __shfl_down(rs, off);
    cs += __shfl_down(cs, off);
  }
  if (lane == 0) { rowsum[o] = rs; cst[o] = cs + bkv[o]; }
}

// ---------------------------------------------------------------------------
// K3b: transpose Wq, Wp -> WqT, WpT (f32)
__global__ __launch_bounds__(256) void transpose_w(
    const float* __restrict__ Wq, const float* __restrict__ Wp,
    float* __restrict__ WqT, float* __restrict__ WpT) {
  __shared__ float tl[64][65];
  const float* src = blockIdx.z ? Wp : Wq;
  float* dst = blockIdx.z ? WpT : WqT;
  int ot = blockIdx.x * 64, ct = blockIdx.y * 64;
  int t = threadIdx.x;
#pragma unroll
  for (int i = 0; i < 16; ++i) {
    int idx = i * 256 + t;
    int o = idx >> 6, c = idx & 63;
    tl[o][c] = src[(size_t)(ot + o) * 768 + ct + c];
  }
  __syncthreads();
#pragma unroll
  for (int i = 0; i < 16; ++i) {
    int idx = i * 256 + t;
    int c = idx >> 6, o = idx & 63;
    dst[(size_t)(ct + c) * 768 + ot + o] = tl[o][c];
  }
}

// ---------------------------------------------------------------------------
// K4: kv = rstd*(W' @ x) + (cst - rstd*mu*rowsum), bf16 MFMA, 128x128 tile.
// K half (o<768) is written TRANSPOSED to KT[b][n][d]; V half to V[b][d][n].
__global__ __launch_bounds__(256) void gemm_kv(
    const __hip_bfloat16* __restrict__ Wb, const __hip_bfloat16* __restrict__ xT,
    const float* __restrict__ rowsum, const float* __restrict__ cst,
    const float* __restrict__ st, __hip_bfloat16* __restrict__ KT,
    __hip_bfloat16* __restrict__ V) {
  __shared__ __hip_bfloat16 As[128 * 64];
  __shared__ __hip_bfloat16 Bs[128 * 64];
  int gx = blockIdx.x;                       // 1536 blocks
  int wg = (gx & 7) * 192 + (gx >> 3);       // bijective XCD swizzle (1536 % 8 == 0)
  int mt = wg % 12;
  int colt = wg / 12;                        // 0..127
  int b = colt >> 3;
  int nt = colt & 7;
  int t = threadIdx.x;
  int wid = t >> 6, lane = t & 63;
  int wm = wid >> 1, wn = wid & 1;

  const __hip_bfloat16* Abase = Wb + (size_t)(mt * 128) * 768;
  const __hip_bfloat16* Bbase = xT + (size_t)b * 1024 * 768 + (size_t)(nt * 128) * 768;

  f32x4 acc[4][4] = {};

  for (int kt = 0; kt < 12; ++kt) {
    const __hip_bfloat16* ag = Abase + kt * 64;
    const __hip_bfloat16* bg = Bbase + kt * 64;
#pragma unroll
    for (int i = 0; i < 4; ++i) {
      int idx = i * 256 + t;
      int row = idx >> 3;
      int kc = (idx & 7) * 8;
      __builtin_amdgcn_global_load_lds(
          (const __attribute__((address_space(1))) void*)(ag + (size_t)row * 768 + kc),
          (__attribute__((address_space(3))) void*)(&As[idx * 8]), 16, 0, 0);
    }
#pragma unroll
    for (int i = 0; i < 4; ++i) {
      int idx = i * 256 + t;
      int row = idx >> 3;
      int kc = (idx & 7) * 8;
      __builtin_amdgcn_global_load_lds(
          (const __attribute__((address_space(1))) void*)(bg + (size_t)row * 768 + kc),
          (__attribute__((address_space(3))) void*)(&Bs[idx * 8]), 16, 0, 0);
    }
    __syncthreads();
#pragma unroll
    for (int kk = 0; kk < 2; ++kk) {
      bf16x8 af[4], bfv[4];
      int r = lane & 15, kc = kk * 32 + (lane >> 4) * 8;
#pragma unroll
      for (int mf = 0; mf < 4; ++mf)
        af[mf] = *(const bf16x8*)&As[(wm * 64 + mf * 16 + r) * 64 + kc];
#pragma unroll
      for (int nf = 0; nf < 4; ++nf)
        bfv[nf] = *(const bf16x8*)&Bs[(wn * 64 + nf * 16 + r) * 64 + kc];
#pragma unroll
      for (int mf = 0; mf < 4; ++mf)
#pragma unroll
        for (int nf = 0; nf < 4; ++nf)
          acc[mf][nf] = __builtin_amdgcn_mfma_f32_16x16x32_bf16(af[mf], bfv[nf], acc[mf][nf], 0, 0, 0);
    }
    __syncthreads();
  }
  float mu = st[b * 2], rstd = st[b * 2 + 1];
  if (mt < 6) {
    // K half: write transposed KT[b][n][o]
    __hip_bfloat16* ktb = KT + (size_t)b * 1024 * 768;
#pragma unroll
    for (int mf = 0; mf < 4; ++mf) {
#pragma unroll
      for (int r = 0; r < 4; ++r) {
        int o = mt * 128 + wm * 64 + mf * 16 + (lane >> 4) * 4 + r;
        float corr = cst[o] - rstd * mu * rowsum[o];
#pragma unroll
        for (int nf = 0; nf < 4; ++nf) {
          int n = nt * 128 + wn * 64 + nf * 16 + (lane & 15);
          ktb[(size_t)n * 768 + o] = __float2bfloat16(rstd * acc[mf][nf][r] + corr);
        }
      }
    }
  } else {
    __hip_bfloat16* vb = V + (size_t)b * 768 * 1024;
#pragma unroll
    for (int mf = 0; mf < 4; ++mf) {
#pragma unroll
      for (int r = 0; r < 4; ++r) {
        int o = mt * 128 + wm * 64 + mf * 16 + (lane >> 4) * 4 + r;
        float corr = cst[o] - rstd * mu * rowsum[o];
        int ov = o - 768;
#pragma unroll
        for (int nf = 0; nf < 4; ++nf) {
          int n = nt * 128 + wn * 64 + nf * 16 + (lane & 15);
          vb[(size_t)ov * 1024 + n] = __float2bfloat16(rstd * acc[mf][nf][r] + corr);
        }
      }
    }
  }
}

// ---------------------------------------------------------------------------
// K5: q = LN(x_cls) @ Wq^T + bq   (per-batch block, o-tile 128) -> bf16
__global__ __launch_bounds__(256) void q_proj(
    const float* __restrict__ x_cls, const float* __restrict__ lnw,
    const float* __restrict__ lnb, const float* __restrict__ WqT,
    const float* __restrict__ bq, __hip_bfloat16* __restrict__ Q) {
  __shared__ float xn[20 * 768];
  int b = blockIdx.x, ot = blockIdx.y;
  int t = threadIdx.x;
  const float* src = x_cls + (size_t)b * 20 * 768;
  for (int idx = t; idx < 15360; idx += 256) xn[idx] = src[idx];
  __syncthreads();
  int wid = t >> 6, lane = t & 63;
  for (int l = wid; l < 20; l += 4) {
    float s = 0.f;
#pragma unroll
    for (int i = 0; i < 12; ++i) s += xn[l * 768 + lane + i * 64];
#pragma unroll
    for (int o = 32; o > 0; o >>= 1) s += __shfl_down(s, o);
    s = __shfl(s, 0);
    float mu = s * (1.0f / 768.0f);
    float v = 0.f;
#pragma unroll
    for (int i = 0; i < 12; ++i) {
      float d = xn[l * 768 + lane + i * 64] - mu;
      v += d * d;
    }
#pragma unroll
    for (int o = 32; o > 0; o >>= 1) v += __shfl_down(v, o);
    v = __shfl(v, 0);
    float rstd = rsqrtf(v * (1.0f / 768.0f) + 1e-5f);
#pragma unroll
    for (int i = 0; i < 12; ++i) {
      int c = lane + i * 64;
      xn[l * 768 + c] = (xn[l * 768 + c] - mu) * rstd * lnw[c] + lnb[c];
    }
  }
  __syncthreads();
  int o = ot * 128 + (t & 127);
  int lg = t >> 7;
  float acc[10] = {};
  for (int c4 = 0; c4 < 768; c4 += 4) {
    float w0 = WqT[(size_t)(c4 + 0) * 768 + o];
    float w1 = WqT[(size_t)(c4 + 1) * 768 + o];
    float w2 = WqT[(size_t)(c4 + 2) * 768 + o];
    float w3 = WqT[(size_t)(c4 + 3) * 768 + o];
#pragma unroll
    for (int j = 0; j < 10; ++j) {
      const float4 a4 = *(const float4*)&xn[(lg * 10 + j) * 768 + c4];
      acc[j] += a4.x * w0 + a4.y * w1 + a4.z * w2 + a4.w * w3;
    }
  }
  float bqo = bq[o];
#pragma unroll
  for (int j = 0; j < 10; ++j)
    Q[((size_t)b * 20 + lg * 10 + j) * 768 + o] = __float2bfloat16(acc[j] + bqo);
}

// ---------------------------------------------------------------------------
// K6: fused MFMA attention per (b,h). 4 waves x 256 threads.
// QK^T: M=32(pad of 20), N=1024, K=192.  PV: M=32, N=192, K=1024.
__global__ __launch_bounds__(256) void attn_mfma(
    const __hip_bfloat16* __restrict__ Qbf, const __hip_bfloat16* __restrict__ KT,
    const __hip_bfloat16* __restrict__ V, float* __restrict__ AO) {
  __shared__ __hip_bfloat16 Qs[32 * 200];    // padded: 400B row stride -> 2-way banks
  __shared__ __hip_bfloat16 Ps[32 * 1032];   // padded: 2064B row stride -> 2-way banks
  __shared__ float redm[4][32];
  __shared__ float reds[4][32];
  int b = blockIdx.x >> 2, h = blockIdx.x & 3;
  int t = threadIdx.x, w = t >> 6, lane = t & 63;
  int r16 = lane & 15, kg = lane >> 4;

  // stage Q (rows 20..31 zero)
  const __hip_bfloat16* qsrc = Qbf + (size_t)b * 20 * 768 + h * 192;
  for (int idx = t; idx < 32 * 192; idx += 256) {
    int l = idx / 192, d = idx % 192;
    Qs[l * 200 + d] = (l < 20) ? qsrc[(size_t)l * 768 + d] : __float2bfloat16(0.f);
  }
  __syncthreads();

  // ---- QK^T: wave w owns n in [w*256, w*256+256) ----
  const __hip_bfloat16* ktb = KT + (size_t)b * 1024 * 768 + h * 192;
  int n0 = w * 256;
  f32x4 acc[2][16] = {};
  for (int ks = 0; ks < 6; ++ks) {
    bf16x8 af0 = *(const bf16x8*)&Qs[(r16) * 200 + ks * 32 + kg * 8];
    bf16x8 af1 = *(const bf16x8*)&Qs[(16 + r16) * 200 + ks * 32 + kg * 8];
#pragma unroll
    for (int nt = 0; nt < 16; ++nt) {
      bf16x8 bfv = *(const bf16x8*)&ktb[(size_t)(n0 + nt * 16 + r16) * 768 + ks * 32 + kg * 8];
      acc[0][nt] = __builtin_amdgcn_mfma_f32_16x16x32_bf16(af0, bfv, acc[0][nt], 0, 0, 0);
      acc[1][nt] = __builtin_amdgcn_mfma_f32_16x16x32_bf16(af1, bfv, acc[1][nt], 0, 0, 0);
    }
  }

  // ---- local row max over this wave's 256 cols ----
#pragma unroll
  for (int mf = 0; mf < 2; ++mf) {
#pragma unroll
    for (int r = 0; r < 4; ++r) {
      float m = acc[mf][0][r];
#pragma unroll
      for (int nt = 1; nt < 16; ++nt) m = fmaxf(m, acc[mf][nt][r]);
#pragma unroll
      for (int o = 1; o < 16; o <<= 1) m = fmaxf(m, __shfl_xor(m, o));
      if (r16 == 0) redm[w][mf * 16 + kg * 4 + r] = m;
    }
  }
  __syncthreads();

  // ---- exp + local sum + write P (bf16) ----
  const float scale = 0.07216878364870322f;
#pragma unroll
  for (int mf = 0; mf < 2; ++mf) {
#pragma unroll
    for (int r = 0; r < 4; ++r) {
      int row = mf * 16 + kg * 4 + r;
      float M = fmaxf(fmaxf(redm[0][row], redm[1][row]),
                      fmaxf(redm[2][row], redm[3][row]));
      float s = 0.f;
#pragma unroll
      for (int nt = 0; nt < 16; ++nt) {
        float e = __expf((acc[mf][nt][r] - M) * scale);
        s += e;
        Ps[row * 1032 + n0 + nt * 16 + r16] = __float2bfloat16(e);
      }
#pragma unroll
      for (int o = 1; o < 16; o <<= 1) s += __shfl_xor(s, o);
      if (r16 == 0) reds[w][row] = s;
    }
  }
  __syncthreads();

  // ---- PV: wave w owns d in [w*48, w*48+48) ----
  const __hip_bfloat16* vb = V + ((size_t)b * 768 + h * 192 + w * 48) * 1024;
  f32x4 pacc[2][3] = {};
  for (int ks = 0; ks < 32; ++ks) {
    bf16x8 pa0 = *(const bf16x8*)&Ps[(r16) * 1032 + ks * 32 + kg * 8];
    bf16x8 pa1 = *(const bf16x8*)&Ps[(16 + r16) * 1032 + ks * 32 + kg * 8];
#pragma unroll
    for (int nt = 0; nt < 3; ++nt) {
      bf16x8 vf = *(const bf16x8*)&vb[(size_t)(nt * 16 + r16) * 1024 + ks * 32 + kg * 8];
      pacc[0][nt] = __builtin_amdgcn_mfma_f32_16x16x32_bf16(pa0, vf, pacc[0][nt], 0, 0, 0);
      pacc[1][nt] = __builtin_amdgcn_mfma_f32_16x16x32_bf16(pa1, vf, pacc[1][nt], 0, 0, 0);
    }
  }

  // ---- epilogue: AO = pacc / rowsum ----
#pragma unroll
  for (int mf = 0; mf < 2; ++mf) {
#pragma unroll
    for (int r = 0; r < 4; ++r) {
      int row = mf * 16 + kg * 4 + r;
      if (row < 20) {
        float rinv = 1.0f / (reds[0][row] + reds[1][row] + reds[2][row] + reds[3][row]);
#pragma unroll
        for (int nt = 0; nt < 3; ++nt) {
          int d = w * 48 + nt * 16 + r16;
          AO[((size_t)b * 20 + row) * 768 + h * 192 + d] = pacc[mf][nt][r] * rinv;
        }
      }
    }
  }
}

// ---------------------------------------------------------------------------
// K7: out_cls = x_cls + AO @ Wp^T + bp  -> d_out[0:245760]
__global__ __launch_bounds__(256) void cls_proj(
    const float* __restrict__ AO, const float* __restrict__ x_cls,
    const float* __restrict__ WpT, const float* __restrict__ bp,
    float* __restrict__ out_cls) {
  __shared__ float a[20 * 768];
  int b = blockIdx.x, ot = blockIdx.y;
  int t = threadIdx.x;
  const float* src = AO + (size_t)b * 15360;
  for (int idx = t; idx < 15360; idx += 256) a[idx] = src[idx];
  __syncthreads();
  int o = ot * 128 + (t & 127);
  int lg = t >> 7;
  float acc[10] = {};
  for (int c4 = 0; c4 < 768; c4 += 4) {
    float w0 = WpT[(size_t)(c4 + 0) * 768 + o];
    float w1 = WpT[(size_t)(c4 + 1) * 768 + o];
    float w2 = WpT[(size_t)(c4 + 2) * 768 + o];
    float w3 = WpT[(size_t)(c4 + 3) * 768 + o];
#pragma unroll
    for (int j = 0; j < 10; ++j) {
      const float4 a4 = *(const float4*)&a[(lg * 10 + j) * 768 + c4];
      acc[j] += a4.x * w0 + a4.y * w1 + a4.z * w2 + a4.w * w3;
    }
  }
  float bpo = bp[o];
#pragma unroll
  for (int j = 0; j < 10; ++j) {
    int l = lg * 10 + j;
    out_cls[((size_t)b * 20 + l) * 768 + o] =
        x_cls[((size_t)b * 20 + l) * 768 + o] + acc[j] + bpo;
  }
}

// ---------------------------------------------------------------------------
// K8: out_patch[b][l][n] = sum_c out_cls[b][l][c] * x[b][c][n]
__global__ __launch_bounds__(256) void patch_mm(
    const float* __restrict__ out_cls, const float* __restrict__ x,
    float* __restrict__ OP) {
  __shared__ float a[20 * 768];
  int b = blockIdx.x, nt2 = blockIdx.y;
  int t = threadIdx.x;
  const float* src = out_cls + (size_t)b * 15360;
  for (int idx = t; idx < 15360; idx += 256) a[idx] = src[idx];
  __syncthreads();
  int n = nt2 * 128 + (t & 127);
  int lg = t >> 7;
  const float* xb = x + (size_t)b * 768 * 1024 + n;
  float acc[10] = {};
  for (int c4 = 0; c4 < 768; c4 += 4) {
    float x0 = xb[(size_t)(c4 + 0) * 1024];
    float x1 = xb[(size_t)(c4 + 1) * 1024];
    float x2 = xb[(size_t)(c4 + 2) * 1024];
    float x3 = xb[(size_t)(c4 + 3) * 1024];
#pragma unroll
    for (int j = 0; j < 10; ++j) {
      const float4 a4 = *(const float4*)&a[(lg * 10 + j) * 768 + c4];
      acc[j] += a4.x * x0 + a4.y * x1 + a4.z * x2 + a4.w * x3;
    }
  }
#pragma unroll
  for (int j = 0; j < 10; ++j)
    OP[((size_t)b * 20 + lg * 10 + j) * 1024 + n] = acc[j];
}

// ---------------------------------------------------------------------------
// K9a: conv weight prep: Wc [768][180] f32 -> Wcb [768][192] bf16 (zero-pad),
//      plus folded BN scale/shift per oc.
__global__ __launch_bounds__(192) void prep_wconv(
    const float* __restrict__ Wc, const float* __restrict__ bc,
    const float* __restrict__ bng, const float* __restrict__ bnb,
    const float* __restrict__ bnm, const float* __restrict__ bnv,
    __hip_bfloat16* __restrict__ Wcb, float* __restrict__ sc,
    float* __restrict__ sh) {
  int oc = blockIdx.x;
  int k = threadIdx.x;
  float v = (k < 180) ? Wc[(size_t)oc * 180 + k] : 0.0f;
  Wcb[(size_t)oc * 192 + k] = __float2bfloat16(v);
  if (k == 0) {
    float s = bng[oc] * rsqrtf(bnv[oc] + 1e-5f);
    sc[oc] = s;
    sh[oc] = (bc[oc] - bnm[oc]) * s + bnb[oc];
  }
}

// ---------------------------------------------------------------------------
// K9b: im2col: Bmat[b][n=(y,x)][k=(ic*9+kh*3+kw)] = OP[b][ic][y+kh-1][x+kw-1]
__global__ __launch_bounds__(256) void im2col(
    const float* __restrict__ OP, __hip_bfloat16* __restrict__ Bm) {
  int idx = blockIdx.x * 256 + threadIdx.x;   // over 16*1024*96 pairs
  int b = idx / (1024 * 96);
  int r = idx % (1024 * 96);
  int n = r / 96;
  int kp = (r % 96) * 2;
  int y = n >> 5, x = n & 31;
  const float* pb = OP + (size_t)b * 20 * 1024;
  float v[2];
#pragma unroll
  for (int j = 0; j < 2; ++j) {
    int k = kp + j;
    float val = 0.0f;
    if (k < 180) {
      int ic = k / 9, k9 = k % 9;
      int kh = k9 / 3, kw = k9 % 3;
      int yy = y + kh - 1, xx = x + kw - 1;
      if (yy >= 0 && yy < 32 && xx >= 0 && xx < 32)
        val = pb[ic * 1024 + yy * 32 + xx];
    }
    v[j] = val;
  }
  __hip_bfloat162 o2;
  o2.x = __float2bfloat16(v[0]);
  o2.y = __float2bfloat16(v[1]);
  *(__hip_bfloat162*)&Bm[(size_t)idx * 2] = o2;
}

// ---------------------------------------------------------------------------
// K9c: implicit-GEMM conv: y = GELU(BN(Wcb @ Bmat^T)), M=768, N=16384, K=192
__global__ __launch_bounds__(256) void gemm_conv(
    const __hip_bfloat16* __restrict__ Wcb, const __hip_bfloat16* __restrict__ Bm,
    const float* __restrict__ sc, const float* __restrict__ sh,
    float* __restrict__ y) {
  __shared__ __hip_bfloat16 As[128 * 64];
  __shared__ __hip_bfloat16 Bs[128 * 64];
  int gx = blockIdx.x;                      // 768 blocks
  int wg = (gx & 7) * 96 + (gx >> 3);       // bijective XCD swizzle (768 % 8 == 0)
  int mt = wg % 6;
  int colt = wg / 6;                        // 0..127
  int b = colt >> 3;
  int nt = colt & 7;
  int t = threadIdx.x;
  int wid = t >> 6, lane = t & 63;
  int wm = wid >> 1, wn = wid & 1;

  const __hip_bfloat16* Abase = Wcb + (size_t)(mt * 128) * 192;
  const __hip_bfloat16* Bbase = Bm + ((size_t)b * 1024 + nt * 128) * 192;

  f32x4 acc[4][4] = {};

  for (int kt = 0; kt < 3; ++kt) {
    const __hip_bfloat16* ag = Abase + kt * 64;
    const __hip_bfloat16* bg = Bbase + kt * 64;
#pragma unroll
    for (int i = 0; i < 4; ++i) {
      int idx = i * 256 + t;
      int row = idx >> 3;
      int kc = (idx & 7) * 8;
      __builtin_amdgcn_global_load_lds(
          (const __attribute__((address_space(1))) void*)(ag + (size_t)row * 192 + kc),
          (__attribute__((address_space(3))) void*)(&As[idx * 8]), 16, 0, 0);
    }
#pragma unroll
    for (int i = 0; i < 4; ++i) {
      int idx = i * 256 + t;
      int row = idx >> 3;
      int kc = (idx & 7) * 8;
      __builtin_amdgcn_global_load_lds(
          (const __attribute__((address_space(1))) void*)(bg + (size_t)row * 192 + kc),
          (__attribute__((address_space(3))) void*)(&Bs[idx * 8]), 16, 0, 0);
    }
    __syncthreads();
#pragma unroll
    for (int kk = 0; kk < 2; ++kk) {
      bf16x8 af[4], bfv[4];
      int r = lane & 15, kc = kk * 32 + (lane >> 4) * 8;
#pragma unroll
      for (int mf = 0; mf < 4; ++mf)
        af[mf] = *(const bf16x8*)&As[(wm * 64 + mf * 16 + r) * 64 + kc];
#pragma unroll
      for (int nf = 0; nf < 4; ++nf)
        bfv[nf] = *(const bf16x8*)&Bs[(wn * 64 + nf * 16 + r) * 64 + kc];
#pragma unroll
      for (int mf = 0; mf < 4; ++mf)
#pragma unroll
        for (int nf = 0; nf < 4; ++nf)
          acc[mf][nf] = __builtin_amdgcn_mfma_f32_16x16x32_bf16(af[mf], bfv[nf], acc[mf][nf], 0, 0, 0);
    }
    __syncthreads();
  }
  float* yb = y + (size_t)b * 768 * 1024;
#pragma unroll
  for (int mf = 0; mf < 4; ++mf) {
#pragma unroll
    for (int r = 0; r < 4; ++r) {
      int oc = mt * 128 + wm * 64 + mf * 16 + (lane >> 4) * 4 + r;
      float s = sc[oc], h = sh[oc];
#pragma unroll
      for (int nf = 0; nf < 4; ++nf) {
        int n = nt * 128 + wn * 64 + nf * 16 + (lane & 15);
        float val = acc[mf][nf][r] * s + h;
        yb[(size_t)oc * 1024 + n] = 0.5f * val * (1.0f + erff(val * 0.70710678118f));
      }
    }
  }
}

// ---------------------------------------------------------------------------
extern "C" void kernel_launch(void* const* d_in, const int* in_sizes, int n_in,
                              void* d_out, int out_size, void* d_ws, size_t ws_size,
                              hipStream_t stream) {
  (void)in_sizes; (void)n_in; (void)out_size; (void)ws_size;
  const float* x_cls = (const float*)d_in[0];
  const float* x     = (const float*)d_in[1];
  const float* lnw   = (const float*)d_in[2];
  const float* lnb   = (const float*)d_in[3];
  const float* nxw   = (const float*)d_in[4];
  const float* nxb   = (const float*)d_in[5];
  const float* Wq    = (const float*)d_in[6];
  const float* bq    = (const float*)d_in[7];
  const float* Wkv   = (const float*)d_in[8];
  const float* bkv   = (const float*)d_in[9];
  const float* Wp    = (const float*)d_in[10];
  const float* bp    = (const float*)d_in[11];
  const float* Wc    = (const float*)d_in[12];
  const float* bc    = (const float*)d_in[13];
  const float* bng   = (const float*)d_in[14];
  const float* bnb   = (const float*)d_in[15];
  const float* bnm   = (const float*)d_in[16];
  const float* bnv   = (const float*)d_in[17];

  char* w = (char*)d_ws;
  __hip_bfloat16* xT = (__hip_bfloat16*)(w + OFF_XT);
  __hip_bfloat16* KT = (__hip_bfloat16*)(w + OFF_KT);
  __hip_bfloat16* V  = (__hip_bfloat16*)(w + OFF_V);
  __hip_bfloat16* Wb = (__hip_bfloat16*)(w + OFF_WB);
  float* rs   = (float*)(w + OFF_RS);
  float* cst  = (float*)(w + OFF_CST);
  float* part = (float*)(w + OFF_PART);
  float* st   = (float*)(w + OFF_ST);
  float* WqT  = (float*)(w + OFF_WQT);
  float* WpT  = (float*)(w + OFF_WPT);
  __hip_bfloat16* Qb = (__hip_bfloat16*)(w + OFF_Q);
  float* AO   = (float*)(w + OFF_AO);
  float* OP   = (float*)(w + OFF_OP);
  __hip_bfloat16* Bm  = (__hip_bfloat16*)(w + OFF_B2);
  __hip_bfloat16* Wcb = (__hip_bfloat16*)(w + OFF_WCB);
  float* scb  = (float*)(w + OFF_SC);
  float* shb  = (float*)(w + OFF_SH);

  float* out_cls = (float*)d_out;
  float* y = out_cls + 245760;

  transpose_reduce<<<dim3(16, 12, 16), 256, 0, stream>>>(x, xT, part);
  finalize_stats<<<1, 64, 0, stream>>>(part, st);
  prep_wkv<<<384, 256, 0, stream>>>(Wkv, nxw, nxb, bkv, Wb, rs, cst);
  transpose_w<<<dim3(12, 12, 2), 256, 0, stream>>>(Wq, Wp, WqT, WpT);
  gemm_kv<<<1536, 256, 0, stream>>>(Wb, xT, rs, cst, st, KT, V);
  // conv weight prep (writes into xT region -> must come after gemm_kv)
  prep_wconv<<<768, 192, 0, stream>>>(Wc, bc, bng, bnb, bnm, bnv, Wcb, scb, shb);
  q_proj<<<dim3(16, 6), 256, 0, stream>>>(x_cls, lnw, lnb, WqT, bq, Qb);
  attn_mfma<<<64, 256, 0, stream>>>(Qb, KT, V, AO);
  cls_proj<<<dim3(16, 6), 256, 0, stream>>>(AO, x_cls, WpT, bp, out_cls);
  patch_mm<<<dim3(16, 8), 256, 0, stream>>>(out_cls, x, OP);
  im2col<<<6144, 256, 0, stream>>>(OP, Bm);
  gemm_conv<<<768, 256, 0, stream>>>(Wcb, Bm, scb, shb, y);
}

// Round 4
// 449.825 us; speedup vs baseline: 1.8939x; 1.0155x over previous
//
#include <hip/hip_runtime.h>
#include <hip/hip_bf16.h>
#include <math.h>

typedef float f32x4 __attribute__((ext_vector_type(4)));
typedef __bf16 bf16x8 __attribute__((ext_vector_type(8)));
typedef __bf16 bf16x4 __attribute__((ext_vector_type(4)));

// Problem constants
// B=16, C=768, CLS=20, HEADS=4, dh=192, N=1024 (32x32), 2C=1536

// Workspace layout (bytes), all 16B aligned. Total ~85.9 MB.
static constexpr size_t OFF_XT   = 0;            // bf16 [16][1024][768]  x transposed
static constexpr size_t OFF_KT   = 25165824;     // bf16 [16][1024][768]  K transposed
static constexpr size_t OFF_V    = 50331648;     // bf16 [16][768][1024]  V
static constexpr size_t OFF_WB   = 75497472;     // bf16 [1536][768]  Wkv*nx_w
static constexpr size_t OFF_RS   = 77856768;     // f32  [1536] rowsum
static constexpr size_t OFF_CST  = 77862912;     // f32  [1536] const term
static constexpr size_t OFF_PART = 77869056;     // f32  [3072][2] partial sums
static constexpr size_t OFF_ST   = 77893632;     // f32  [16][2] mu,rstd
static constexpr size_t OFF_WQT  = 77893760;     // f32  [768][768]
static constexpr size_t OFF_WPT  = 80253056;     // f32  [768][768]
static constexpr size_t OFF_Q    = 82612352;     // bf16 [16][20][768]
static constexpr size_t OFF_AO   = 83595392;     // f32  [16][20][768]
static constexpr size_t OFF_OP   = 84578432;     // f32  [16][20][1024]

// Conv buffers live inside the xT region (xT is dead after gemm_kv; im2col /
// gemm_conv are ordered after attention in the launch sequence).
static constexpr size_t OFF_B2   = OFF_XT;             // bf16 [16][1024][192] im2col
static constexpr size_t OFF_WCB  = OFF_XT + 6291456;   // bf16 [768][192]
static constexpr size_t OFF_SC   = OFF_XT + 6586368;   // f32  [768] bn scale
static constexpr size_t OFF_SH   = OFF_XT + 6589440;   // f32  [768] bn shift

// ---------------------------------------------------------------------------
// K1: x [b][c][n] f32 -> xT [b][n][c] bf16, plus per-block partial sum/sumsq
__global__ __launch_bounds__(256) void transpose_reduce(
    const float* __restrict__ x, __hip_bfloat16* __restrict__ xT,
    float* __restrict__ part) {
  __shared__ __hip_bfloat16 tile[64][66];
  __shared__ float red[4][2];
  int b = blockIdx.x, cb = blockIdx.y, nb = blockIdx.z;
  int t = threadIdx.x;
  const float* src = x + ((size_t)b * 768 + cb * 64) * 1024 + nb * 64;
  float s1 = 0.f, s2 = 0.f;
#pragma unroll
  for (int i = 0; i < 16; ++i) {
    int idx = i * 256 + t;
    int c = idx >> 6, n = idx & 63;
    float v = src[(size_t)c * 1024 + n];
    s1 += v; s2 += v * v;
    tile[c][n] = __float2bfloat16(v);
  }
#pragma unroll
  for (int o = 32; o > 0; o >>= 1) {
    s1 += __shfl_down(s1, o);
    s2 += __shfl_down(s2, o);
  }
  int wid = t >> 6, lane = t & 63;
  if (lane == 0) { red[wid][0] = s1; red[wid][1] = s2; }
  __syncthreads();
  if (t == 0) {
    float a = 0.f, bb = 0.f;
    for (int w = 0; w < 4; ++w) { a += red[w][0]; bb += red[w][1]; }
    int pidx = b * 192 + cb * 16 + nb;
    part[pidx * 2] = a; part[pidx * 2 + 1] = bb;
  }
  __hip_bfloat16* dst = xT + ((size_t)b * 1024 + nb * 64) * 768 + cb * 64;
#pragma unroll
  for (int i = 0; i < 16; ++i) {
    int idx = i * 256 + t;
    int n = idx >> 6, c = idx & 63;
    dst[(size_t)n * 768 + c] = tile[c][n];
  }
}

// ---------------------------------------------------------------------------
// K2: finalize per-batch mu / rstd
__global__ void finalize_stats(const float* __restrict__ part, float* __restrict__ st) {
  int t = threadIdx.x;
  if (t < 16) {
    float s1 = 0.f, s2 = 0.f;
    for (int i = 0; i < 192; ++i) {
      s1 += part[(t * 192 + i) * 2];
      s2 += part[(t * 192 + i) * 2 + 1];
    }
    float mu = s1 * (1.0f / 786432.0f);
    float var = s2 * (1.0f / 786432.0f) - mu * mu;
    st[t * 2] = mu;
    st[t * 2 + 1] = rsqrtf(var + 1e-5f);
  }
}

// ---------------------------------------------------------------------------
// K3: W' = Wkv * nx_w (bf16), rowsum = sum_c W', cst = sum_c Wkv*nx_b + bkv
__global__ __launch_bounds__(256) void prep_wkv(
    const float* __restrict__ Wkv, const float* __restrict__ nxw,
    const float* __restrict__ nxb, const float* __restrict__ bkv,
    __hip_bfloat16* __restrict__ Wb, float* __restrict__ rowsum,
    float* __restrict__ cst) {
  int o = blockIdx.x * 4 + (threadIdx.x >> 6);
  int lane = threadIdx.x & 63;
  const float* wrow = Wkv + (size_t)o * 768;
  float rs = 0.f, cs = 0.f;
#pragma unroll
  for (int i = 0; i < 12; ++i) {
    int c = lane + i * 64;
    float w = wrow[c];
    float wb = w * nxw[c];
    Wb[(size_t)o * 768 + c] = __float2bfloat16(wb);
    rs += wb;
    cs += w * nxb[c];
  }
#pragma unroll
  for (int off = 32; off > 0; off >>= 1) {
    rs += __shfl_down(rs, off);
    cs += __shfl_down(cs, off);
  }
  if (lane == 0) { rowsum[o] = rs; cst[o] = cs + bkv[o]; }
}

// ---------------------------------------------------------------------------
// K3b: transpose Wq, Wp -> WqT, WpT (f32)
__global__ __launch_bounds__(256) void transpose_w(
    const float* __restrict__ Wq, const float* __restrict__ Wp,
    float* __restrict__ WqT, float* __restrict__ WpT) {
  __shared__ float tl[64][65];
  const float* src = blockIdx.z ? Wp : Wq;
  float* dst = blockIdx.z ? WpT : WqT;
  int ot = blockIdx.x * 64, ct = blockIdx.y * 64;
  int t = threadIdx.x;
#pragma unroll
  for (int i = 0; i < 16; ++i) {
    int idx = i * 256 + t;
    int o = idx >> 6, c = idx & 63;
    tl[o][c] = src[(size_t)(ot + o) * 768 + ct + c];
  }
  __syncthreads();
#pragma unroll
  for (int i = 0; i < 16; ++i) {
    int idx = i * 256 + t;
    int c = idx >> 6, o = idx & 63;
    dst[(size_t)(ct + c) * 768 + ot + o] = tl[o][c];
  }
}

// ---------------------------------------------------------------------------
// K4: kv = rstd*(W' @ x) + (cst - rstd*mu*rowsum), bf16 MFMA, 128x128 tile,
// double-buffered 2-phase pipeline (stage k+1 before compute k, 1 barrier/step).
// K half (o<768) is written TRANSPOSED to KT[b][n][d]; V half to V[b][d][n].

#define STAGE_KV(buf, kt) do {                                                  \
  const __hip_bfloat16* ag_ = Abase + (kt) * 64;                                \
  const __hip_bfloat16* bg_ = Bbase + (kt) * 64;                                \
  _Pragma("unroll")                                                             \
  for (int i_ = 0; i_ < 4; ++i_) {                                              \
    int idx_ = i_ * 256 + t;                                                    \
    int row_ = idx_ >> 3;                                                       \
    int kc_ = (idx_ & 7) * 8;                                                   \
    __builtin_amdgcn_global_load_lds(                                           \
        (const __attribute__((address_space(1))) void*)(ag_ + (size_t)row_ * 768 + kc_), \
        (__attribute__((address_space(3))) void*)(&As[buf][idx_ * 8]), 16, 0, 0); \
  }                                                                             \
  _Pragma("unroll")                                                             \
  for (int i_ = 0; i_ < 4; ++i_) {                                              \
    int idx_ = i_ * 256 + t;                                                    \
    int row_ = idx_ >> 3;                                                       \
    int kc_ = (idx_ & 7) * 8;                                                   \
    __builtin_amdgcn_global_load_lds(                                           \
        (const __attribute__((address_space(1))) void*)(bg_ + (size_t)row_ * 768 + kc_), \
        (__attribute__((address_space(3))) void*)(&Bs[buf][idx_ * 8]), 16, 0, 0); \
  }                                                                             \
} while (0)

#define COMPUTE_KV(buf) do {                                                    \
  _Pragma("unroll")                                                             \
  for (int kk_ = 0; kk_ < 2; ++kk_) {                                           \
    bf16x8 af_[4], bfv_[4];                                                     \
    int r_ = lane & 15, kc_ = kk_ * 32 + (lane >> 4) * 8;                       \
    _Pragma("unroll")                                                           \
    for (int mf_ = 0; mf_ < 4; ++mf_)                                           \
      af_[mf_] = *(const bf16x8*)&As[buf][(wm * 64 + mf_ * 16 + r_) * 64 + kc_]; \
    _Pragma("unroll")                                                           \
    for (int nf_ = 0; nf_ < 4; ++nf_)                                           \
      bfv_[nf_] = *(const bf16x8*)&Bs[buf][(wn * 64 + nf_ * 16 + r_) * 64 + kc_]; \
    _Pragma("unroll")                                                           \
    for (int mf_ = 0; mf_ < 4; ++mf_)                                           \
      _Pragma("unroll")                                                         \
      for (int nf_ = 0; nf_ < 4; ++nf_)                                         \
        acc[mf_][nf_] = __builtin_amdgcn_mfma_f32_16x16x32_bf16(af_[mf_], bfv_[nf_], acc[mf_][nf_], 0, 0, 0); \
  }                                                                             \
} while (0)

__global__ __launch_bounds__(256) void gemm_kv(
    const __hip_bfloat16* __restrict__ Wb, const __hip_bfloat16* __restrict__ xT,
    const float* __restrict__ rowsum, const float* __restrict__ cst,
    const float* __restrict__ st, __hip_bfloat16* __restrict__ KT,
    __hip_bfloat16* __restrict__ V) {
  __shared__ __hip_bfloat16 As[2][128 * 64];
  __shared__ __hip_bfloat16 Bs[2][128 * 64];
  int gx = blockIdx.x;                       // 1536 blocks
  int wg = (gx & 7) * 192 + (gx >> 3);       // bijective XCD swizzle (1536 % 8 == 0)
  int mt = wg % 12;
  int colt = wg / 12;                        // 0..127
  int b = colt >> 3;
  int nt = colt & 7;
  int t = threadIdx.x;
  int wid = t >> 6, lane = t & 63;
  int wm = wid >> 1, wn = wid & 1;

  const __hip_bfloat16* Abase = Wb + (size_t)(mt * 128) * 768;
  const __hip_bfloat16* Bbase = xT + (size_t)b * 1024 * 768 + (size_t)(nt * 128) * 768;

  f32x4 acc[4][4] = {};

  STAGE_KV(0, 0);
  __syncthreads();
#pragma unroll 1
  for (int kt2 = 0; kt2 < 6; ++kt2) {
    STAGE_KV(1, 2 * kt2 + 1);
    COMPUTE_KV(0);
    __syncthreads();
    if (kt2 < 5) STAGE_KV(0, 2 * kt2 + 2);
    COMPUTE_KV(1);
    __syncthreads();
  }

  float mu = st[b * 2], rstd = st[b * 2 + 1];
  if (mt < 6) {
    // K half: write transposed KT[b][n][o]
    __hip_bfloat16* ktb = KT + (size_t)b * 1024 * 768;
#pragma unroll
    for (int mf = 0; mf < 4; ++mf) {
#pragma unroll
      for (int r = 0; r < 4; ++r) {
        int o = mt * 128 + wm * 64 + mf * 16 + (lane >> 4) * 4 + r;
        float corr = cst[o] - rstd * mu * rowsum[o];
#pragma unroll
        for (int nf = 0; nf < 4; ++nf) {
          int n = nt * 128 + wn * 64 + nf * 16 + (lane & 15);
          ktb[(size_t)n * 768 + o] = __float2bfloat16(rstd * acc[mf][nf][r] + corr);
        }
      }
    }
  } else {
    __hip_bfloat16* vb = V + (size_t)b * 768 * 1024;
#pragma unroll
    for (int mf = 0; mf < 4; ++mf) {
#pragma unroll
      for (int r = 0; r < 4; ++r) {
        int o = mt * 128 + wm * 64 + mf * 16 + (lane >> 4) * 4 + r;
        float corr = cst[o] - rstd * mu * rowsum[o];
        int ov = o - 768;
#pragma unroll
        for (int nf = 0; nf < 4; ++nf) {
          int n = nt * 128 + wn * 64 + nf * 16 + (lane & 15);
          vb[(size_t)ov * 1024 + n] = __float2bfloat16(rstd * acc[mf][nf][r] + corr);
        }
      }
    }
  }
}

// ---------------------------------------------------------------------------
// K5: q = LN(x_cls) @ Wq^T + bq   (per-batch block, o-tile 128) -> bf16
__global__ __launch_bounds__(256) void q_proj(
    const float* __restrict__ x_cls, const float* __restrict__ lnw,
    const float* __restrict__ lnb, const float* __restrict__ WqT,
    const float* __restrict__ bq, __hip_bfloat16* __restrict__ Q) {
  __shared__ float xn[20 * 768];
  int b = blockIdx.x, ot = blockIdx.y;
  int t = threadIdx.x;
  const float* src = x_cls + (size_t)b * 20 * 768;
  for (int idx = t; idx < 15360; idx += 256) xn[idx] = src[idx];
  __syncthreads();
  int wid = t >> 6, lane = t & 63;
  for (int l = wid; l < 20; l += 4) {
    float s = 0.f;
#pragma unroll
    for (int i = 0; i < 12; ++i) s += xn[l * 768 + lane + i * 64];
#pragma unroll
    for (int o = 32; o > 0; o >>= 1) s += __shfl_down(s, o);
    s = __shfl(s, 0);
    float mu = s * (1.0f / 768.0f);
    float v = 0.f;
#pragma unroll
    for (int i = 0; i < 12; ++i) {
      float d = xn[l * 768 + lane + i * 64] - mu;
      v += d * d;
    }
#pragma unroll
    for (int o = 32; o > 0; o >>= 1) v += __shfl_down(v, o);
    v = __shfl(v, 0);
    float rstd = rsqrtf(v * (1.0f / 768.0f) + 1e-5f);
#pragma unroll
    for (int i = 0; i < 12; ++i) {
      int c = lane + i * 64;
      xn[l * 768 + c] = (xn[l * 768 + c] - mu) * rstd * lnw[c] + lnb[c];
    }
  }
  __syncthreads();
  int o = ot * 128 + (t & 127);
  int lg = t >> 7;
  float acc[10] = {};
  for (int c4 = 0; c4 < 768; c4 += 4) {
    float w0 = WqT[(size_t)(c4 + 0) * 768 + o];
    float w1 = WqT[(size_t)(c4 + 1) * 768 + o];
    float w2 = WqT[(size_t)(c4 + 2) * 768 + o];
    float w3 = WqT[(size_t)(c4 + 3) * 768 + o];
#pragma unroll
    for (int j = 0; j < 10; ++j) {
      const float4 a4 = *(const float4*)&xn[(lg * 10 + j) * 768 + c4];
      acc[j] += a4.x * w0 + a4.y * w1 + a4.z * w2 + a4.w * w3;
    }
  }
  float bqo = bq[o];
#pragma unroll
  for (int j = 0; j < 10; ++j)
    Q[((size_t)b * 20 + lg * 10 + j) * 768 + o] = __float2bfloat16(acc[j] + bqo);
}

// ---------------------------------------------------------------------------
// K6: fused MFMA attention per (b,h). 8 waves x 512 threads.
// QK^T: M=32(pad of 20), N=1024 (wave w owns 128 cols), K=192.
// PV: M=32, N=192 (4 d-tiles of 48), K=1024 split in halves across wave pairs.
__global__ __launch_bounds__(512) void attn_mfma(
    const __hip_bfloat16* __restrict__ Qbf, const __hip_bfloat16* __restrict__ KT,
    const __hip_bfloat16* __restrict__ V, float* __restrict__ AO) {
  __shared__ __hip_bfloat16 Qs[32 * 200];    // 400B row stride -> 2-lane/bank (free)
  __shared__ __hip_bfloat16 Ps[32 * 1032];   // 2064B row stride -> 2-lane/bank (free)
  __shared__ float redm[8][32];
  __shared__ float reds[8][32];
  __shared__ float pvp[4][32][48];           // K-half partials from waves 4..7
  int b = blockIdx.x >> 2, h = blockIdx.x & 3;
  int t = threadIdx.x, w = t >> 6, lane = t & 63;
  int r16 = lane & 15, kg = lane >> 4;

  // stage Q (rows 20..31 zero)
  const __hip_bfloat16* qsrc = Qbf + (size_t)b * 20 * 768 + h * 192;
  for (int idx = t; idx < 32 * 192; idx += 512) {
    int l = idx / 192, d = idx % 192;
    Qs[l * 200 + d] = (l < 20) ? qsrc[(size_t)l * 768 + d] : __float2bfloat16(0.f);
  }
  __syncthreads();

  // ---- QK^T: wave w owns n in [w*128, w*128+128) ----
  const __hip_bfloat16* ktb = KT + (size_t)b * 1024 * 768 + h * 192;
  int n0 = w * 128;
  f32x4 acc[2][8] = {};
  for (int ks = 0; ks < 6; ++ks) {
    bf16x8 af0 = *(const bf16x8*)&Qs[(r16) * 200 + ks * 32 + kg * 8];
    bf16x8 af1 = *(const bf16x8*)&Qs[(16 + r16) * 200 + ks * 32 + kg * 8];
#pragma unroll
    for (int nt = 0; nt < 8; ++nt) {
      bf16x8 bfv = *(const bf16x8*)&ktb[(size_t)(n0 + nt * 16 + r16) * 768 + ks * 32 + kg * 8];
      acc[0][nt] = __builtin_amdgcn_mfma_f32_16x16x32_bf16(af0, bfv, acc[0][nt], 0, 0, 0);
      acc[1][nt] = __builtin_amdgcn_mfma_f32_16x16x32_bf16(af1, bfv, acc[1][nt], 0, 0, 0);
    }
  }

  // ---- local row max over this wave's 128 cols ----
#pragma unroll
  for (int mf = 0; mf < 2; ++mf) {
#pragma unroll
    for (int r = 0; r < 4; ++r) {
      float m = acc[mf][0][r];
#pragma unroll
      for (int nt = 1; nt < 8; ++nt) m = fmaxf(m, acc[mf][nt][r]);
#pragma unroll
      for (int o = 1; o < 16; o <<= 1) m = fmaxf(m, __shfl_xor(m, o));
      if (r16 == 0) redm[w][mf * 16 + kg * 4 + r] = m;
    }
  }
  __syncthreads();

  // ---- exp + local sum + write P (bf16) ----
  const float scale = 0.07216878364870322f;
#pragma unroll
  for (int mf = 0; mf < 2; ++mf) {
#pragma unroll
    for (int r = 0; r < 4; ++r) {
      int row = mf * 16 + kg * 4 + r;
      float M = fmaxf(fmaxf(fmaxf(redm[0][row], redm[1][row]),
                            fmaxf(redm[2][row], redm[3][row])),
                      fmaxf(fmaxf(redm[4][row], redm[5][row]),
                            fmaxf(redm[6][row], redm[7][row])));
      float s = 0.f;
#pragma unroll
      for (int nt = 0; nt < 8; ++nt) {
        float e = __expf((acc[mf][nt][r] - M) * scale);
        s += e;
        Ps[row * 1032 + n0 + nt * 16 + r16] = __float2bfloat16(e);
      }
#pragma unroll
      for (int o = 1; o < 16; o <<= 1) s += __shfl_xor(s, o);
      if (r16 == 0) reds[w][row] = s;
    }
  }
  __syncthreads();

  // ---- PV: wave pair (wd, wd+4): d-tile wd*48, K halves ----
  int wd = w & 3, kh = w >> 2;
  const __hip_bfloat16* vb = V + ((size_t)b * 768 + h * 192 + wd * 48) * 1024;
  f32x4 pacc[2][3] = {};
  for (int ks = kh * 16; ks < kh * 16 + 16; ++ks) {
    bf16x8 pa0 = *(const bf16x8*)&Ps[(r16) * 1032 + ks * 32 + kg * 8];
    bf16x8 pa1 = *(const bf16x8*)&Ps[(16 + r16) * 1032 + ks * 32 + kg * 8];
#pragma unroll
    for (int nt = 0; nt < 3; ++nt) {
      bf16x8 vf = *(const bf16x8*)&vb[(size_t)(nt * 16 + r16) * 1024 + ks * 32 + kg * 8];
      pacc[0][nt] = __builtin_amdgcn_mfma_f32_16x16x32_bf16(pa0, vf, pacc[0][nt], 0, 0, 0);
      pacc[1][nt] = __builtin_amdgcn_mfma_f32_16x16x32_bf16(pa1, vf, pacc[1][nt], 0, 0, 0);
    }
  }
  if (w >= 4) {
#pragma unroll
    for (int mf = 0; mf < 2; ++mf)
#pragma unroll
      for (int r = 0; r < 4; ++r)
#pragma unroll
        for (int nt = 0; nt < 3; ++nt)
          pvp[wd][mf * 16 + kg * 4 + r][nt * 16 + r16] = pacc[mf][nt][r];
  }
  __syncthreads();

  // ---- epilogue: AO = (pacc_half0 + pacc_half1) / rowsum ----
  if (w < 4) {
#pragma unroll
    for (int mf = 0; mf < 2; ++mf) {
#pragma unroll
      for (int r = 0; r < 4; ++r) {
        int row = mf * 16 + kg * 4 + r;
        if (row < 20) {
          float rs8 = reds[0][row] + reds[1][row] + reds[2][row] + reds[3][row] +
                      reds[4][row] + reds[5][row] + reds[6][row] + reds[7][row];
          float rinv = 1.0f / rs8;
#pragma unroll
          for (int nt = 0; nt < 3; ++nt) {
            int d = wd * 48 + nt * 16 + r16;
            AO[((size_t)b * 20 + row) * 768 + h * 192 + d] =
                (pacc[mf][nt][r] + pvp[wd][row][nt * 16 + r16]) * rinv;
          }
        }
      }
    }
  }
}

// ---------------------------------------------------------------------------
// K7: out_cls = x_cls + AO @ Wp^T + bp  -> d_out[0:245760]
__global__ __launch_bounds__(256) void cls_proj(
    const float* __restrict__ AO, const float* __restrict__ x_cls,
    const float* __restrict__ WpT, const float* __restrict__ bp,
    float* __restrict__ out_cls) {
  __shared__ float a[20 * 768];
  int b = blockIdx.x, ot = blockIdx.y;
  int t = threadIdx.x;
  const float* src = AO + (size_t)b * 15360;
  for (int idx = t; idx < 15360; idx += 256) a[idx] = src[idx];
  __syncthreads();
  int o = ot * 128 + (t & 127);
  int lg = t >> 7;
  float acc[10] = {};
  for (int c4 = 0; c4 < 768; c4 += 4) {
    float w0 = WpT[(size_t)(c4 + 0) * 768 + o];
    float w1 = WpT[(size_t)(c4 + 1) * 768 + o];
    float w2 = WpT[(size_t)(c4 + 2) * 768 + o];
    float w3 = WpT[(size_t)(c4 + 3) * 768 + o];
#pragma unroll
    for (int j = 0; j < 10; ++j) {
      const float4 a4 = *(const float4*)&a[(lg * 10 + j) * 768 + c4];
      acc[j] += a4.x * w0 + a4.y * w1 + a4.z * w2 + a4.w * w3;
    }
  }
  float bpo = bp[o];
#pragma unroll
  for (int j = 0; j < 10; ++j) {
    int l = lg * 10 + j;
    out_cls[((size_t)b * 20 + l) * 768 + o] =
        x_cls[((size_t)b * 20 + l) * 768 + o] + acc[j] + bpo;
  }
}

// ---------------------------------------------------------------------------
// K8: out_patch[b][l][n] = sum_c out_cls[b][l][c] * x[b][c][n]
__global__ __launch_bounds__(256) void patch_mm(
    const float* __restrict__ out_cls, const float* __restrict__ x,
    float* __restrict__ OP) {
  __shared__ float a[20 * 768];
  int b = blockIdx.x, nt2 = blockIdx.y;
  int t = threadIdx.x;
  const float* src = out_cls + (size_t)b * 15360;
  for (int idx = t; idx < 15360; idx += 256) a[idx] = src[idx];
  __syncthreads();
  int n = nt2 * 128 + (t & 127);
  int lg = t >> 7;
  const float* xb = x + (size_t)b * 768 * 1024 + n;
  float acc[10] = {};
  for (int c4 = 0; c4 < 768; c4 += 4) {
    float x0 = xb[(size_t)(c4 + 0) * 1024];
    float x1 = xb[(size_t)(c4 + 1) * 1024];
    float x2 = xb[(size_t)(c4 + 2) * 1024];
    float x3 = xb[(size_t)(c4 + 3) * 1024];
#pragma unroll
    for (int j = 0; j < 10; ++j) {
      const float4 a4 = *(const float4*)&a[(lg * 10 + j) * 768 + c4];
      acc[j] += a4.x * x0 + a4.y * x1 + a4.z * x2 + a4.w * x3;
    }
  }
#pragma unroll
  for (int j = 0; j < 10; ++j)
    OP[((size_t)b * 20 + lg * 10 + j) * 1024 + n] = acc[j];
}

// ---------------------------------------------------------------------------
// K9a: conv weight prep: Wc [768][180] f32 -> Wcb [768][192] bf16 (zero-pad),
//      plus folded BN scale/shift per oc.
__global__ __launch_bounds__(192) void prep_wconv(
    const float* __restrict__ Wc, const float* __restrict__ bc,
    const float* __restrict__ bng, const float* __restrict__ bnb,
    const float* __restrict__ bnm, const float* __restrict__ bnv,
    __hip_bfloat16* __restrict__ Wcb, float* __restrict__ sc,
    float* __restrict__ sh) {
  int oc = blockIdx.x;
  int k = threadIdx.x;
  float v = (k < 180) ? Wc[(size_t)oc * 180 + k] : 0.0f;
  Wcb[(size_t)oc * 192 + k] = __float2bfloat16(v);
  if (k == 0) {
    float s = bng[oc] * rsqrtf(bnv[oc] + 1e-5f);
    sc[oc] = s;
    sh[oc] = (bc[oc] - bnm[oc]) * s + bnb[oc];
  }
}

// ---------------------------------------------------------------------------
// K9b: im2col: Bmat[b][n=(y,x)][k=(ic*9+kh*3+kw)] = OP[b][ic][y+kh-1][x+kw-1]
__global__ __launch_bounds__(256) void im2col(
    const float* __restrict__ OP, __hip_bfloat16* __restrict__ Bm) {
  int idx = blockIdx.x * 256 + threadIdx.x;   // over 16*1024*96 pairs
  int b = idx / (1024 * 96);
  int r = idx % (1024 * 96);
  int n = r / 96;
  int kp = (r % 96) * 2;
  int y = n >> 5, x = n & 31;
  const float* pb = OP + (size_t)b * 20 * 1024;
  float v[2];
#pragma unroll
  for (int j = 0; j < 2; ++j) {
    int k = kp + j;
    float val = 0.0f;
    if (k < 180) {
      int ic = k / 9, k9 = k % 9;
      int kh = k9 / 3, kw = k9 % 3;
      int yy = y + kh - 1, xx = x + kw - 1;
      if (yy >= 0 && yy < 32 && xx >= 0 && xx < 32)
        val = pb[ic * 1024 + yy * 32 + xx];
    }
    v[j] = val;
  }
  __hip_bfloat162 o2;
  o2.x = __float2bfloat16(v[0]);
  o2.y = __float2bfloat16(v[1]);
  *(__hip_bfloat162*)&Bm[(size_t)idx * 2] = o2;
}

// ---------------------------------------------------------------------------
// K9c: implicit-GEMM conv: y = GELU(BN(Wcb @ Bmat^T)), M=768, N=16384, K=192,
// double-buffered 2-phase (3 K-steps).

#define STAGE_CV(buf, kt) do {                                                  \
  const __hip_bfloat16* ag_ = Abase + (kt) * 64;                                \
  const __hip_bfloat16* bg_ = Bbase + (kt) * 64;                                \
  _Pragma("unroll")                                                             \
  for (int i_ = 0; i_ < 4; ++i_) {                                              \
    int idx_ = i_ * 256 + t;                                                    \
    int row_ = idx_ >> 3;                                                       \
    int kc_ = (idx_ & 7) * 8;                                                   \
    __builtin_amdgcn_global_load_lds(                                           \
        (const __attribute__((address_space(1))) void*)(ag_ + (size_t)row_ * 192 + kc_), \
        (__attribute__((address_space(3))) void*)(&As[buf][idx_ * 8]), 16, 0, 0); \
  }                                                                             \
  _Pragma("unroll")                                                             \
  for (int i_ = 0; i_ < 4; ++i_) {                                              \
    int idx_ = i_ * 256 + t;                                                    \
    int row_ = idx_ >> 3;                                                       \
    int kc_ = (idx_ & 7) * 8;                                                   \
    __builtin_amdgcn_global_load_lds(                                           \
        (const __attribute__((address_space(1))) void*)(bg_ + (size_t)row_ * 192 + kc_), \
        (__attribute__((address_space(3))) void*)(&Bs[buf][idx_ * 8]), 16, 0, 0); \
  }                                                                             \
} while (0)

__global__ __launch_bounds__(256) void gemm_conv(
    const __hip_bfloat16* __restrict__ Wcb, const __hip_bfloat16* __restrict__ Bm,
    const float* __restrict__ sc, const float* __restrict__ sh,
    float* __restrict__ y) {
  __shared__ __hip_bfloat16 As[2][128 * 64];
  __shared__ __hip_bfloat16 Bs[2][128 * 64];
  int gx = blockIdx.x;                      // 768 blocks
  int wg = (gx & 7) * 96 + (gx >> 3);       // bijective XCD swizzle (768 % 8 == 0)
  int mt = wg % 6;
  int colt = wg / 6;                        // 0..127
  int b = colt >> 3;
  int nt = colt & 7;
  int t = threadIdx.x;
  int wid = t >> 6, lane = t & 63;
  int wm = wid >> 1, wn = wid & 1;

  const __hip_bfloat16* Abase = Wcb + (size_t)(mt * 128) * 192;
  const __hip_bfloat16* Bbase = Bm + ((size_t)b * 1024 + nt * 128) * 192;

  f32x4 acc[4][4] = {};

  STAGE_CV(0, 0);
  __syncthreads();
  STAGE_CV(1, 1);
  COMPUTE_KV(0);
  __syncthreads();
  STAGE_CV(0, 2);
  COMPUTE_KV(1);
  __syncthreads();
  COMPUTE_KV(0);

  float* yb = y + (size_t)b * 768 * 1024;
#pragma unroll
  for (int mf = 0; mf < 4; ++mf) {
#pragma unroll
    for (int r = 0; r < 4; ++r) {
      int oc = mt * 128 + wm * 64 + mf * 16 + (lane >> 4) * 4 + r;
      float s = sc[oc], h = sh[oc];
#pragma unroll
      for (int nf = 0; nf < 4; ++nf) {
        int n = nt * 128 + wn * 64 + nf * 16 + (lane & 15);
        float val = acc[mf][nf][r] * s + h;
        yb[(size_t)oc * 1024 + n] = 0.5f * val * (1.0f + erff(val * 0.70710678118f));
      }
    }
  }
}

// ---------------------------------------------------------------------------
extern "C" void kernel_launch(void* const* d_in, const int* in_sizes, int n_in,
                              void* d_out, int out_size, void* d_ws, size_t ws_size,
                              hipStream_t stream) {
  (void)in_sizes; (void)n_in; (void)out_size; (void)ws_size;
  const float* x_cls = (const float*)d_in[0];
  const float* x     = (const float*)d_in[1];
  const float* lnw   = (const float*)d_in[2];
  const float* lnb   = (const float*)d_in[3];
  const float* nxw   = (const float*)d_in[4];
  const float* nxb   = (const float*)d_in[5];
  const float* Wq    = (const float*)d_in[6];
  const float* bq    = (const float*)d_in[7];
  const float* Wkv   = (const float*)d_in[8];
  const float* bkv   = (const float*)d_in[9];
  const float* Wp    = (const float*)d_in[10];
  const float* bp    = (const float*)d_in[11];
  const float* Wc    = (const float*)d_in[12];
  const float* bc    = (const float*)d_in[13];
  const float* bng   = (const float*)d_in[14];
  const float* bnb   = (const float*)d_in[15];
  const float* bnm   = (const float*)d_in[16];
  const float* bnv   = (const float*)d_in[17];

  char* w = (char*)d_ws;
  __hip_bfloat16* xT = (__hip_bfloat16*)(w + OFF_XT);
  __hip_bfloat16* KT = (__hip_bfloat16*)(w + OFF_KT);
  __hip_bfloat16* V  = (__hip_bfloat16*)(w + OFF_V);
  __hip_bfloat16* Wb = (__hip_bfloat16*)(w + OFF_WB);
  float* rs   = (float*)(w + OFF_RS);
  float* cst  = (float*)(w + OFF_CST);
  float* part = (float*)(w + OFF_PART);
  float* st   = (float*)(w + OFF_ST);
  float* WqT  = (float*)(w + OFF_WQT);
  float* WpT  = (float*)(w + OFF_WPT);
  __hip_bfloat16* Qb = (__hip_bfloat16*)(w + OFF_Q);
  float* AO   = (float*)(w + OFF_AO);
  float* OP   = (float*)(w + OFF_OP);
  __hip_bfloat16* Bm  = (__hip_bfloat16*)(w + OFF_B2);
  __hip_bfloat16* Wcb = (__hip_bfloat16*)(w + OFF_WCB);
  float* scb  = (float*)(w + OFF_SC);
  float* shb  = (float*)(w + OFF_SH);

  float* out_cls = (float*)d_out;
  float* y = out_cls + 245760;

  transpose_reduce<<<dim3(16, 12, 16), 256, 0, stream>>>(x, xT, part);
  finalize_stats<<<1, 64, 0, stream>>>(part, st);
  prep_wkv<<<384, 256, 0, stream>>>(Wkv, nxw, nxb, bkv, Wb, rs, cst);
  transpose_w<<<dim3(12, 12, 2), 256, 0, stream>>>(Wq, Wp, WqT, WpT);
  gemm_kv<<<1536, 256, 0, stream>>>(Wb, xT, rs, cst, st, KT, V);
  // conv weight prep (writes into xT region -> must come after gemm_kv)
  prep_wconv<<<768, 192, 0, stream>>>(Wc, bc, bng, bnb, bnm, bnv, Wcb, scb, shb);
  q_proj<<<dim3(16, 6), 256, 0, stream>>>(x_cls, lnw, lnb, WqT, bq, Qb);
  attn_mfma<<<64, 512, 0, stream>>>(Qb, KT, V, AO);
  cls_proj<<<dim3(16, 6), 256, 0, stream>>>(AO, x_cls, WpT, bp, out_cls);
  patch_mm<<<dim3(16, 8), 256, 0, stream>>>(out_cls, x, OP);
  im2col<<<6144, 256, 0, stream>>>(OP, Bm);
  gemm_conv<<<768, 256, 0, stream>>>(Wcb, Bm, scb, shb, y);
}